// Round 16
// baseline (627.790 us; speedup 1.0000x reference)
//
#include <hip/hip_runtime.h>
#include <hip/hip_bf16.h>

// ProteinGNNTransformer — round 16: barrier-free attention.
// PV computed as O^T = mfma(V^T, P^T): V^T frags are b128 GLOBAL loads from a
// pre-transposed V (written by the qkv GEMM epilogue into the dead obf region),
// eliminating the V LDS tile, its 4-way-conflicted transpose writes, and BOTH
// per-iter __syncthreads. fac rescale is now lane-local (no Fl LDS / shfl).
// Diagnosis: SQ_LDS_BANK_CONFLICT pegged at 2^23 (saturated) + per-CU LDS-pipe
// arithmetic showed attention was LDS/barrier bound, not VALU bound.

#define NPROT 3000
#define NAA   25
#define NPROP 1071
#define NTOT  4096
#define DIM   256
#define NH    8
#define DHD   32
#define FFD   1024
#define NEDGE 131072
#define LNEPS 1e-5f
#define KSPLIT 2
#define KVQ (NTOT/KSPLIT)

typedef unsigned short u16;
typedef unsigned int u32;
typedef __attribute__((ext_vector_type(8))) short short8v;
typedef __attribute__((ext_vector_type(4))) float float4v;
typedef __attribute__((ext_vector_type(2))) unsigned int uint2v;

__device__ __forceinline__ u16 f2bu(float x){
  union { __hip_bfloat16 h; u16 u; } c; c.h = __float2bfloat16(x); return c.u;
}
__device__ __forceinline__ float bu2f(u16 u){
  union { u32 i; float f; } c; c.i = ((u32)u) << 16; return c.f;
}
__device__ __forceinline__ float4v mfma16(short8v a, short8v b, float4v c){
  return __builtin_amdgcn_mfma_f32_16x16x32_bf16(a, b, c, 0, 0, 0);
}
// pack two f32 to two bf16 (truncation) — v_perm idiom
__device__ __forceinline__ u32 packbf(float lo, float hi){
  u32 ul = __builtin_bit_cast(u32, lo);
  u32 uh = __builtin_bit_cast(u32, hi);
  return (ul >> 16) | (uh & 0xFFFF0000u);
}

// ---------------- embedding concat ----------------
__global__ __launch_bounds__(256) void k_embed(const float* __restrict__ pe, const float* __restrict__ ae,
                                               const float* __restrict__ qe,
                                               float* __restrict__ cur, float* __restrict__ tot){
  int i = blockIdx.x*256 + threadIdx.x;
  int row = i >> 8;
  float v;
  if (row < NPROT)           v = pe[i];
  else if (row < NPROT+NAA)  v = ae[i - NPROT*DIM];
  else                       v = qe[i - (NPROT+NAA)*DIM];
  cur[i] = v; tot[i] = v;
}

__global__ __launch_bounds__(256) void k_zero(int* __restrict__ p, int n){
  int i = blockIdx.x*256 + threadIdx.x; if (i < n) p[i] = 0;
}

// ---------------- fused weight transpose+convert ----------------
__global__ __launch_bounds__(256) void k_wconv_all(const float* __restrict__ Wqkv, const float* __restrict__ Wo,
                                                   const float* __restrict__ W1, const float* __restrict__ W2,
                                                   u16* __restrict__ wqkvt, u16* __restrict__ wot,
                                                   u16* __restrict__ w1t, u16* __restrict__ w2t){
  int b = blockIdx.x;
  const float* W; u16* Wt; int K, N, n;
  if (b < 768)       { W = Wqkv; Wt = wqkvt; K = 256;  N = 768;  n = b; }
  else if (b < 1024) { W = Wo;   Wt = wot;   K = 256;  N = 256;  n = b - 768; }
  else if (b < 2048) { W = W1;   Wt = w1t;   K = 256;  N = 1024; n = b - 1024; }
  else               { W = W2;   Wt = w2t;   K = 1024; N = 256;  n = b - 2048; }
  for (int k = threadIdx.x; k < K; k += 256)
    Wt[(size_t)n*K + k] = f2bu(W[(size_t)k*N + n]);
}

// ---------------- CSR build ----------------
__global__ __launch_bounds__(256) void k_hist(const int* __restrict__ rows, int* __restrict__ cnt){
  int e = blockIdx.x*256 + threadIdx.x; if (e < NEDGE) atomicAdd(&cnt[rows[e]], 1);
}

__global__ __launch_bounds__(64) void k_scan(const int* __restrict__ cnt, int* __restrict__ rowptr,
                                             int* __restrict__ cursor){
  int lane = threadIdx.x;
  int sum = 0;
  for (int i = 0; i < 64; ++i) sum += cnt[lane*64 + i];
  int pref = sum;
  #pragma unroll
  for (int off = 1; off < 64; off <<= 1){
    int u = __shfl_up(pref, off);
    if (lane >= off) pref += u;
  }
  int run = pref - sum;
  for (int i = 0; i < 64; ++i){
    int c = cnt[lane*64 + i];
    rowptr[lane*64 + i] = run;
    cursor[lane*64 + i] = run;
    run += c;
  }
  if (lane == 63) rowptr[NTOT] = run;
}

__global__ __launch_bounds__(256) void k_scatter(const int* __restrict__ rows, const int* __restrict__ cols,
                                                 const float* __restrict__ vals, int* __restrict__ cursor,
                                                 int* __restrict__ ccol, float* __restrict__ cval){
  int e = blockIdx.x*256 + threadIdx.x; if (e >= NEDGE) return;
  int p = atomicAdd(&cursor[rows[e]], 1);
  ccol[p] = cols[e]; cval[p] = vals[e];
}

// ---------------- SpMM: f32 out + bf16 shadow ----------------
__global__ __launch_bounds__(256) void k_spmm(const int* __restrict__ rowptr, const int* __restrict__ ccol,
                                              const float* __restrict__ cval, const float* __restrict__ x,
                                              float* __restrict__ out, u16* __restrict__ outb){
  int r = blockIdx.x, c = threadIdx.x;
  int s = rowptr[r], e = rowptr[r+1];
  float acc = 0.f;
  for (int i = s; i < e; ++i)
    acc += cval[i] * x[((size_t)ccol[i] << 8) + c];
  out[((size_t)r << 8) + c] = acc;
  outb[((size_t)r << 8) + c] = f2bu(acc);
}

// ---------------- MFMA GEMM, 64x64 tile; VSPLIT writes cols>=512 as V^T ----------------
template<int RELU, int BIAS, int BF16OUT, int VSPLIT>
__global__ __launch_bounds__(256) void k_gemm64(const u16* __restrict__ A, const u16* __restrict__ Wt,
                                                const float* __restrict__ bias, void* __restrict__ Cv,
                                                u16* __restrict__ vtg,
                                                int M, int K, int Nc){
  __shared__ u16 Al[64*64];
  __shared__ u16 Bl[64*64];
  const int tid = threadIdx.x;
  const int w  = tid >> 6, l = tid & 63, lr = l & 15, g = l >> 4;
  const int row0 = blockIdx.y*64, col0 = blockIdx.x*64;
  const int wm = (w >> 1)*32, wn = (w & 1)*32;
  const int sm = tid >> 2;
  const int so = (tid & 3)*2;
  float4v acc[2][2] = {};

  for (int k0 = 0; k0 < K; k0 += 64){
    const u16* As = A  + (size_t)(row0 + sm)*K + k0 + so*8;
    const u16* Bs = Wt + (size_t)(col0 + sm)*K + k0 + so*8;
    #pragma unroll
    for (int j = 0; j < 2; ++j){
      int o = so + j;
      int slot = o ^ (sm & 7);
      *(short8v*)(Al + sm*64 + slot*8) = *(const short8v*)(As + j*8);
      *(short8v*)(Bl + sm*64 + slot*8) = *(const short8v*)(Bs + j*8);
    }
    __syncthreads();
    #pragma unroll
    for (int kk = 0; kk < 2; ++kk){
      short8v af[2], bfr[2];
      #pragma unroll
      for (int i = 0; i < 2; ++i){
        int am = wm + 16*i + lr;
        af[i]  = *(const short8v*)(Al + am*64 + (((4*kk + g) ^ (am & 7))*8));
        int bn = wn + 16*i + lr;
        bfr[i] = *(const short8v*)(Bl + bn*64 + (((4*kk + g) ^ (bn & 7))*8));
      }
      acc[0][0] = mfma16(af[0], bfr[0], acc[0][0]);
      acc[0][1] = mfma16(af[0], bfr[1], acc[0][1]);
      acc[1][0] = mfma16(af[1], bfr[0], acc[1][0]);
      acc[1][1] = mfma16(af[1], bfr[1], acc[1][1]);
    }
    __syncthreads();
  }

  #pragma unroll
  for (int mi = 0; mi < 2; ++mi){
    #pragma unroll
    for (int ni = 0; ni < 2; ++ni){
      int colbase = col0 + wn + 16*ni;
      int col = colbase + lr;
      if (VSPLIT && colbase >= 512){
        // write transposed: vtg[(col-512)][row..row+3] packed b64
        int row = row0 + wm + 16*mi + 4*g;
        u32 lo = packbf(acc[mi][ni][0], acc[mi][ni][1]);
        u32 hi = packbf(acc[mi][ni][2], acc[mi][ni][3]);
        *(uint2v*)(vtg + (size_t)(col - 512)*NTOT + row) = (uint2v){lo, hi};
      } else {
        float bv = BIAS ? bias[col] : 0.f;
        #pragma unroll
        for (int j = 0; j < 4; ++j){
          int row = row0 + wm + 16*mi + 4*g + j;
          float v = acc[mi][ni][j] + bv;
          if (RELU) v = fmaxf(v, 0.f);
          if (BF16OUT) ((u16*)Cv)[(size_t)row*Nc + col] = f2bu(v);
          else         ((float*)Cv)[(size_t)row*Nc + col] = v;
        }
      }
    }
  }
}

// ---------------- MFMA flash attention, split-K x2, BARRIER-FREE ----------------
// grid (NTOT/64, NH, KSPLIT); 4 waves, wave w owns q rows [qb+16w..+16).
// QK^T: s = mfma(K, Q) -> lane (lr,g) holds P[q=lr][kv=16i+4g+j] (raw).
// PV:   O^T = mfma(V^T, P^T): A-frag = b128 from pre-transposed vtg (global),
//       B-frag = b128 from per-wave P LDS. D[dh][q=lr] -> fac is lane-local.
__global__ __launch_bounds__(256) void k_attn_mfma(const u16* __restrict__ qbf,
                                                   const u16* __restrict__ vtg,
                                                   u16* __restrict__ op,
                                                   float* __restrict__ mbuf, float* __restrict__ lbuf){
  __shared__ u16 Pl[4][16*64];               // per-wave P — no cross-wave sharing
  const int h   = blockIdx.y;
  const int ks  = blockIdx.z;
  const int qb  = blockIdx.x * 64;
  const int tid = threadIdx.x;
  const int w   = tid >> 6;
  const int l   = tid & 63;
  const int lr  = l & 15;
  const int g   = l >> 4;
  const float SC  = 0.17677669529663687f;    // 1/sqrt(32)
  const float SCL = 0.25503837f;             // SC * log2(e)
  const float DEFER = 31.368f;               // 8/SCL — P bounded by 2^8
  u16* opart = op + (size_t)ks*NTOT*DIM;

  short8v qf = *(const short8v*)(qbf + (size_t)(qb + 16*w + lr)*768 + h*DHD + 8*g);
  short8v ones;
  #pragma unroll
  for (int j = 0; j < 8; ++j) ones[j] = (short)0x3F80;

  float4v oa0 = {0.f,0.f,0.f,0.f}, oa1 = {0.f,0.f,0.f,0.f};
  float4v accl = {0.f,0.f,0.f,0.f};
  float mrun = -1e30f;
  u16* pw = &Pl[w][0];

  const u16* kp = qbf + (size_t)(ks*KVQ + lr)*768 + 256 + h*DHD + 8*g;
  const u16* vr0 = vtg + (size_t)(h*DHD + lr)*NTOT + ks*KVQ + 8*g;        // dh = lr
  const u16* vr1 = vr0 + (size_t)16*NTOT;                                  // dh = lr+16
  short8v kf0 = *(const short8v*)(kp);
  short8v kf1 = *(const short8v*)(kp + (size_t)16*768);
  short8v kf2 = *(const short8v*)(kp + (size_t)32*768);
  short8v kf3 = *(const short8v*)(kp + (size_t)48*768);

  const int NIT = KVQ/64;
  for (int t = 0; t < NIT; ++t){
    // ---- S^T = K·Q ----
    float4v s0 = mfma16(kf0, qf, (float4v){0.f,0.f,0.f,0.f});
    float4v s1 = mfma16(kf1, qf, (float4v){0.f,0.f,0.f,0.f});
    float4v s2 = mfma16(kf2, qf, (float4v){0.f,0.f,0.f,0.f});
    float4v s3 = mfma16(kf3, qf, (float4v){0.f,0.f,0.f,0.f});
    // prefetch K (t+1); branchless (overread stays inside qbf's 8MB region)
    kp += (size_t)64*768;
    kf0 = *(const short8v*)(kp);
    kf1 = *(const short8v*)(kp + (size_t)16*768);
    kf2 = *(const short8v*)(kp + (size_t)32*768);
    kf3 = *(const short8v*)(kp + (size_t)48*768);

    // ---- per-lane softmax (q = lr) ----
    float m0 = fmaxf(fmaxf(fmaxf(s0[0],s0[1]),s0[2]),s0[3]);
    float m1 = fmaxf(fmaxf(fmaxf(s1[0],s1[1]),s1[2]),s1[3]);
    float m2 = fmaxf(fmaxf(fmaxf(s2[0],s2[1]),s2[2]),s2[3]);
    float m3 = fmaxf(fmaxf(fmaxf(s3[0],s3[1]),s3[2]),s3[3]);
    float tm = fmaxf(fmaxf(fmaxf(m0,m1),m2),m3);
    tm = fmaxf(tm, __shfl_xor(tm, 16));
    tm = fmaxf(tm, __shfl_xor(tm, 32));
    const bool nomax = __all(tm <= mrun + DEFER);
    float fac = 1.f;
    if (!nomax){
      float mn = fmaxf(mrun, tm);
      fac = exp2f((mrun - mn)*SCL);
      mrun = mn;
    }
    float mns = mrun*SCL;
    #pragma unroll
    for (int j = 0; j < 4; ++j){
      s0[j] = exp2f(__builtin_fmaf(s0[j], SCL, -mns));
      s1[j] = exp2f(__builtin_fmaf(s1[j], SCL, -mns));
      s2[j] = exp2f(__builtin_fmaf(s2[j], SCL, -mns));
      s3[j] = exp2f(__builtin_fmaf(s3[j], SCL, -mns));
    }

    // ---- P -> per-wave LDS (truncation-pack, b64, octet^lr swizzle) ----
    {
      int gh = g >> 1, gl = 4*(g & 1);
      uint2v* d0 = (uint2v*)(pw + lr*64 + ((0 + gh) ^ (lr & 7))*8 + gl);
      uint2v* d1 = (uint2v*)(pw + lr*64 + ((2 + gh) ^ (lr & 7))*8 + gl);
      uint2v* d2 = (uint2v*)(pw + lr*64 + ((4 + gh) ^ (lr & 7))*8 + gl);
      uint2v* d3 = (uint2v*)(pw + lr*64 + ((6 + gh) ^ (lr & 7))*8 + gl);
      *d0 = (uint2v){packbf(s0[0],s0[1]), packbf(s0[2],s0[3])};
      *d1 = (uint2v){packbf(s1[0],s1[1]), packbf(s1[2],s1[3])};
      *d2 = (uint2v){packbf(s2[0],s2[1]), packbf(s2[2],s2[3])};
      *d3 = (uint2v){packbf(s3[0],s3[1]), packbf(s3[2],s3[3])};
    }

    // ---- rescale (lane-local: all accumulators are q = lr) ----
    if (!nomax){
      oa0[0]*=fac; oa0[1]*=fac; oa0[2]*=fac; oa0[3]*=fac;
      oa1[0]*=fac; oa1[1]*=fac; oa1[2]*=fac; oa1[3]*=fac;
      accl[0]*=fac; accl[1]*=fac; accl[2]*=fac; accl[3]*=fac;
    }

    // ---- O^T += V^T P^T; l += 1·P ----
    const u16* vb = vr0 + (size_t)t*64;
    const u16* vb1 = vr1 + (size_t)t*64;
    #pragma unroll
    for (int kk = 0; kk < 2; ++kk){
      int slotp = (4*kk + g) ^ (lr & 7);
      short8v pa = *(const short8v*)(pw + lr*64 + slotp*8);
      short8v va0 = *(const short8v*)(vb  + 32*kk);
      short8v va1 = *(const short8v*)(vb1 + 32*kk);
      oa0  = mfma16(va0, pa, oa0);
      oa1  = mfma16(va1, pa, oa1);
      accl = mfma16(ones, pa, accl);
    }
  }

  // ---- epilogue: packed bf16 partials (O[q=lr][dh=4g+j]) + m/l ----
  {
    size_t row = (size_t)(qb + 16*w + lr);
    u32 a0 = packbf(oa0[0], oa0[1]), a1 = packbf(oa0[2], oa0[3]);
    u32 b0 = packbf(oa1[0], oa1[1]), b1 = packbf(oa1[2], oa1[3]);
    *(uint2v*)(opart + row*DIM + h*DHD + 4*g)      = (uint2v){a0, a1};
    *(uint2v*)(opart + row*DIM + h*DHD + 16 + 4*g) = (uint2v){b0, b1};
  }
  if (g == 0){
    size_t mi = (size_t)(ks*NH + h)*NTOT + qb + 16*w + lr;
    mbuf[mi] = mrun*SC;
    lbuf[mi] = accl[0];
  }
}

// ---------------- split-K merge (2-way) ----------------
__global__ __launch_bounds__(256) void k_attn_merge(const u16* __restrict__ op,
                                                    const float* __restrict__ mbuf, const float* __restrict__ lbuf,
                                                    u16* __restrict__ obf){
  int i = blockIdx.x*256 + threadIdx.x;
  int r = i >> 8, c = i & 255, h = c >> 5;
  float m[KSPLIT], wgt[KSPLIT];
  float M = -1e30f;
  #pragma unroll
  for (int k = 0; k < KSPLIT; ++k){
    m[k] = mbuf[(size_t)(k*NH + h)*NTOT + r];
    M = fmaxf(M, m[k]);
  }
  float L = 0.f, acc = 0.f;
  #pragma unroll
  for (int k = 0; k < KSPLIT; ++k){
    wgt[k] = __expf(m[k] - M);
    L   += wgt[k]*lbuf[(size_t)(k*NH + h)*NTOT + r];
    acc += wgt[k]*bu2f(op[(size_t)k*NTOT*DIM + i]);
  }
  obf[i] = f2bu(acc / L);
}

// ---------------- fused residual + LayerNorm (+bf16 shadow) ----------------
template<int DUAL>
__global__ __launch_bounds__(256) void k_add_ln(const float* __restrict__ a, const float* __restrict__ b,
                                                const float* __restrict__ g, const float* __restrict__ be,
                                                float* __restrict__ out, u16* __restrict__ out2){
  __shared__ float red[4];
  int r = blockIdx.x, c = threadIdx.x;
  float v = a[((size_t)r << 8) + c] + b[((size_t)r << 8) + c];
  float s = v;
  #pragma unroll
  for (int off = 32; off; off >>= 1) s += __shfl_down(s, off);
  if ((c & 63) == 0) red[c >> 6] = s;
  __syncthreads();
  float mean = (red[0]+red[1]+red[2]+red[3]) * (1.f/DIM);
  __syncthreads();
  float d = v - mean;
  float s2 = d*d;
  #pragma unroll
  for (int off = 32; off; off >>= 1) s2 += __shfl_down(s2, off);
  if ((c & 63) == 0) red[c >> 6] = s2;
  __syncthreads();
  float var = (red[0]+red[1]+red[2]+red[3]) * (1.f/DIM);
  float rv = d * rsqrtf(var + LNEPS) * g[c] + be[c];
  out[((size_t)r << 8) + c] = rv;
  if (DUAL) out2[((size_t)r << 8) + c] = f2bu(rv);
}

// ---------------- fused LN2 + update (+final output copy) ----------------
template<int FINAL>
__global__ __launch_bounds__(256) void k_add_ln_upd(const float* __restrict__ a, const float* __restrict__ b,
                                                    const float* __restrict__ g, const float* __restrict__ be,
                                                    float* __restrict__ cur, float* __restrict__ tot,
                                                    float* __restrict__ out){
  __shared__ float red[4];
  int r = blockIdx.x, c = threadIdx.x;
  size_t idx = ((size_t)r << 8) + c;
  float v = a[idx] + b[idx];
  float s = v;
  #pragma unroll
  for (int off = 32; off; off >>= 1) s += __shfl_down(s, off);
  if ((c & 63) == 0) red[c >> 6] = s;
  __syncthreads();
  float mean = (red[0]+red[1]+red[2]+red[3]) * (1.f/DIM);
  __syncthreads();
  float d = v - mean;
  float s2 = d*d;
  #pragma unroll
  for (int off = 32; off; off >>= 1) s2 += __shfl_down(s2, off);
  if ((c & 63) == 0) red[c >> 6] = s2;
  __syncthreads();
  float var = (red[0]+red[1]+red[2]+red[3]) * (1.f/DIM);
  float rv = d * rsqrtf(var + LNEPS) * g[c] + be[c];
  float cu = cur[idx] + rv;
  cur[idx] = cu;
  float tv = tot[idx] + cu;
  tot[idx] = tv;
  if (FINAL){
    out[idx] = tv;
    out[(size_t)NTOT*DIM + idx] = tv;
  }
}

extern "C" void kernel_launch(void* const* d_in, const int* in_sizes, int n_in,
                              void* d_out, int out_size, void* d_ws, size_t ws_size,
                              hipStream_t stream){
  const int*   adj_row = (const int*)  d_in[0];
  const int*   adj_col = (const int*)  d_in[1];
  const float* adj_val = (const float*)d_in[2];
  const float* pe   = (const float*)d_in[3];
  const float* ae   = (const float*)d_in[4];
  const float* qe   = (const float*)d_in[5];
  const float* Wqkv = (const float*)d_in[6];
  const float* Wo   = (const float*)d_in[7];
  const float* W1   = (const float*)d_in[8];
  const float* b1   = (const float*)d_in[9];
  const float* W2   = (const float*)d_in[10];
  const float* b2   = (const float*)d_in[11];
  const float* g1   = (const float*)d_in[12];
  const float* be1  = (const float*)d_in[13];
  const float* g2   = (const float*)d_in[14];
  const float* be2  = (const float*)d_in[15];
  float* out = (float*)d_out;

  // ---- workspace (~36.7 MB, layout unchanged; vtg aliases obf) ----
  char* w = (char*)d_ws;
  float* cur  = (float*)w; w += (size_t)NTOT*DIM*4;
  float* tot  = (float*)w; w += (size_t)NTOT*DIM*4;
  float* tf   = (float*)w; w += (size_t)NTOT*DIM*4;
  float* pbuf = (float*)w; w += (size_t)NTOT*DIM*4;        // proj/ffn2 out; attn partials (2x bf16)
  float* x1   = (float*)w; w += (size_t)NTOT*DIM*4;
  u16* tbf    = (u16*)w;   w += (size_t)NTOT*DIM*2;        // spmm bf16; attn m/l
  u16* obf    = (u16*)w;   w += (size_t)NTOT*DIM*2;        // merge out; ALSO vtg (V^T) during attn
  u16* x1b    = (u16*)w;   w += (size_t)NTOT*DIM*2;
  u16* hq     = (u16*)w;   w += (size_t)NTOT*FFD*2;        // qbf ∪ h
  u16* wqkvt  = (u16*)w;   w += (size_t)768*256*2;
  u16* wot    = (u16*)w;   w += (size_t)256*256*2;
  u16* w1t    = (u16*)w;   w += (size_t)1024*256*2;
  u16* w2t    = (u16*)w;   w += (size_t)256*1024*2;
  int* rowptr = (int*)w;   w += (size_t)(NTOT+1)*4;
  int* cnt    = (int*)w;   w += (size_t)NTOT*4;
  int* cursor = (int*)w;   w += (size_t)NTOT*4;
  int* ccol   = (int*)w;   w += (size_t)NEDGE*4;
  float* cval = (float*)w; w += (size_t)NEDGE*4;
  u16* qbf  = hq;
  u16* vtg  = obf;                             // V^T [256][4096] bf16 = 2 MB (dead obf phase)
  u16* opbf = (u16*)pbuf;                      // 2 bf16 partials = 4 MB
  float* mbuf = (float*)tbf;                   // [KSPLIT][NH][NTOT] f32
  float* lbuf = mbuf + (size_t)KSPLIT*NH*NTOT;

  k_zero<<<16, 256, 0, stream>>>(cnt, NTOT);
  k_embed<<<NTOT, 256, 0, stream>>>(pe, ae, qe, cur, tot);
  k_hist<<<NEDGE/256, 256, 0, stream>>>(adj_row, cnt);
  k_scan<<<1, 64, 0, stream>>>(cnt, rowptr, cursor);
  k_scatter<<<NEDGE/256, 256, 0, stream>>>(adj_row, adj_col, adj_val, cursor, ccol, cval);
  k_wconv_all<<<2304, 256, 0, stream>>>(Wqkv, Wo, W1, W2, wqkvt, wot, w1t, w2t);

  for (int blk = 0; blk < 3; ++blk){
    k_spmm<<<NTOT, 256, 0, stream>>>(rowptr, ccol, cval, cur, tf, tbf);
    k_gemm64<0,0,1,1><<<dim3(768/64, NTOT/64), 256, 0, stream>>>(tbf, wqkvt, nullptr, qbf, vtg, NTOT, 256, 768);
    k_attn_mfma<<<dim3(NTOT/64, NH, KSPLIT), 256, 0, stream>>>(qbf, vtg, opbf, mbuf, lbuf);
    k_attn_merge<<<NTOT*DIM/256, 256, 0, stream>>>(opbf, mbuf, lbuf, obf);
    k_gemm64<0,0,0,0><<<dim3(256/64, NTOT/64), 256, 0, stream>>>(obf, wot, nullptr, pbuf, nullptr, NTOT, 256, 256);
    k_add_ln<1><<<NTOT, 256, 0, stream>>>(tf, pbuf, g1, be1, x1, x1b);
    k_gemm64<1,1,1,0><<<dim3(1024/64, NTOT/64), 256, 0, stream>>>(x1b, w1t, b1, hq, nullptr, NTOT, 256, 1024);
    k_gemm64<0,1,0,0><<<dim3(256/64, NTOT/64), 256, 0, stream>>>(hq, w2t, b2, pbuf, nullptr, NTOT, 1024, 256);
    if (blk < 2)
      k_add_ln_upd<0><<<NTOT, 256, 0, stream>>>(x1, pbuf, g2, be2, cur, tot, nullptr);
    else
      k_add_ln_upd<1><<<NTOT, 256, 0, stream>>>(x1, pbuf, g2, be2, cur, tot, out);
  }
}

// Round 17
// 625.037 us; speedup vs baseline: 1.0044x; 1.0044x over previous
//
#include <hip/hip_runtime.h>
#include <hip/hip_bf16.h>

// ProteinGNNTransformer — round 17: r16 barrier-free attention + the missing
// piece: V^T fragments register-prefetched one tile ahead (r16 loaded them at
// point of use -> raw L2 latency in the PV loop, VALUBusy 76->37%, 129us).
// Everything else unchanged from r16.

#define NPROT 3000
#define NAA   25
#define NPROP 1071
#define NTOT  4096
#define DIM   256
#define NH    8
#define DHD   32
#define FFD   1024
#define NEDGE 131072
#define LNEPS 1e-5f
#define KSPLIT 2
#define KVQ (NTOT/KSPLIT)

typedef unsigned short u16;
typedef unsigned int u32;
typedef __attribute__((ext_vector_type(8))) short short8v;
typedef __attribute__((ext_vector_type(4))) float float4v;
typedef __attribute__((ext_vector_type(2))) unsigned int uint2v;

__device__ __forceinline__ u16 f2bu(float x){
  union { __hip_bfloat16 h; u16 u; } c; c.h = __float2bfloat16(x); return c.u;
}
__device__ __forceinline__ float bu2f(u16 u){
  union { u32 i; float f; } c; c.i = ((u32)u) << 16; return c.f;
}
__device__ __forceinline__ float4v mfma16(short8v a, short8v b, float4v c){
  return __builtin_amdgcn_mfma_f32_16x16x32_bf16(a, b, c, 0, 0, 0);
}
// pack two f32 to two bf16 (truncation) — v_perm idiom
__device__ __forceinline__ u32 packbf(float lo, float hi){
  u32 ul = __builtin_bit_cast(u32, lo);
  u32 uh = __builtin_bit_cast(u32, hi);
  return (ul >> 16) | (uh & 0xFFFF0000u);
}

// ---------------- embedding concat ----------------
__global__ __launch_bounds__(256) void k_embed(const float* __restrict__ pe, const float* __restrict__ ae,
                                               const float* __restrict__ qe,
                                               float* __restrict__ cur, float* __restrict__ tot){
  int i = blockIdx.x*256 + threadIdx.x;
  int row = i >> 8;
  float v;
  if (row < NPROT)           v = pe[i];
  else if (row < NPROT+NAA)  v = ae[i - NPROT*DIM];
  else                       v = qe[i - (NPROT+NAA)*DIM];
  cur[i] = v; tot[i] = v;
}

__global__ __launch_bounds__(256) void k_zero(int* __restrict__ p, int n){
  int i = blockIdx.x*256 + threadIdx.x; if (i < n) p[i] = 0;
}

// ---------------- fused weight transpose+convert ----------------
__global__ __launch_bounds__(256) void k_wconv_all(const float* __restrict__ Wqkv, const float* __restrict__ Wo,
                                                   const float* __restrict__ W1, const float* __restrict__ W2,
                                                   u16* __restrict__ wqkvt, u16* __restrict__ wot,
                                                   u16* __restrict__ w1t, u16* __restrict__ w2t){
  int b = blockIdx.x;
  const float* W; u16* Wt; int K, N, n;
  if (b < 768)       { W = Wqkv; Wt = wqkvt; K = 256;  N = 768;  n = b; }
  else if (b < 1024) { W = Wo;   Wt = wot;   K = 256;  N = 256;  n = b - 768; }
  else if (b < 2048) { W = W1;   Wt = w1t;   K = 256;  N = 1024; n = b - 1024; }
  else               { W = W2;   Wt = w2t;   K = 1024; N = 256;  n = b - 2048; }
  for (int k = threadIdx.x; k < K; k += 256)
    Wt[(size_t)n*K + k] = f2bu(W[(size_t)k*N + n]);
}

// ---------------- CSR build ----------------
__global__ __launch_bounds__(256) void k_hist(const int* __restrict__ rows, int* __restrict__ cnt){
  int e = blockIdx.x*256 + threadIdx.x; if (e < NEDGE) atomicAdd(&cnt[rows[e]], 1);
}

__global__ __launch_bounds__(64) void k_scan(const int* __restrict__ cnt, int* __restrict__ rowptr,
                                             int* __restrict__ cursor){
  int lane = threadIdx.x;
  int sum = 0;
  for (int i = 0; i < 64; ++i) sum += cnt[lane*64 + i];
  int pref = sum;
  #pragma unroll
  for (int off = 1; off < 64; off <<= 1){
    int u = __shfl_up(pref, off);
    if (lane >= off) pref += u;
  }
  int run = pref - sum;
  for (int i = 0; i < 64; ++i){
    int c = cnt[lane*64 + i];
    rowptr[lane*64 + i] = run;
    cursor[lane*64 + i] = run;
    run += c;
  }
  if (lane == 63) rowptr[NTOT] = run;
}

__global__ __launch_bounds__(256) void k_scatter(const int* __restrict__ rows, const int* __restrict__ cols,
                                                 const float* __restrict__ vals, int* __restrict__ cursor,
                                                 int* __restrict__ ccol, float* __restrict__ cval){
  int e = blockIdx.x*256 + threadIdx.x; if (e >= NEDGE) return;
  int p = atomicAdd(&cursor[rows[e]], 1);
  ccol[p] = cols[e]; cval[p] = vals[e];
}

// ---------------- SpMM: f32 out + bf16 shadow ----------------
__global__ __launch_bounds__(256) void k_spmm(const int* __restrict__ rowptr, const int* __restrict__ ccol,
                                              const float* __restrict__ cval, const float* __restrict__ x,
                                              float* __restrict__ out, u16* __restrict__ outb){
  int r = blockIdx.x, c = threadIdx.x;
  int s = rowptr[r], e = rowptr[r+1];
  float acc = 0.f;
  for (int i = s; i < e; ++i)
    acc += cval[i] * x[((size_t)ccol[i] << 8) + c];
  out[((size_t)r << 8) + c] = acc;
  outb[((size_t)r << 8) + c] = f2bu(acc);
}

// ---------------- MFMA GEMM, 64x64 tile; VSPLIT writes cols>=512 as V^T ----------------
template<int RELU, int BIAS, int BF16OUT, int VSPLIT>
__global__ __launch_bounds__(256) void k_gemm64(const u16* __restrict__ A, const u16* __restrict__ Wt,
                                                const float* __restrict__ bias, void* __restrict__ Cv,
                                                u16* __restrict__ vtg,
                                                int M, int K, int Nc){
  __shared__ u16 Al[64*64];
  __shared__ u16 Bl[64*64];
  const int tid = threadIdx.x;
  const int w  = tid >> 6, l = tid & 63, lr = l & 15, g = l >> 4;
  const int row0 = blockIdx.y*64, col0 = blockIdx.x*64;
  const int wm = (w >> 1)*32, wn = (w & 1)*32;
  const int sm = tid >> 2;
  const int so = (tid & 3)*2;
  float4v acc[2][2] = {};

  for (int k0 = 0; k0 < K; k0 += 64){
    const u16* As = A  + (size_t)(row0 + sm)*K + k0 + so*8;
    const u16* Bs = Wt + (size_t)(col0 + sm)*K + k0 + so*8;
    #pragma unroll
    for (int j = 0; j < 2; ++j){
      int o = so + j;
      int slot = o ^ (sm & 7);
      *(short8v*)(Al + sm*64 + slot*8) = *(const short8v*)(As + j*8);
      *(short8v*)(Bl + sm*64 + slot*8) = *(const short8v*)(Bs + j*8);
    }
    __syncthreads();
    #pragma unroll
    for (int kk = 0; kk < 2; ++kk){
      short8v af[2], bfr[2];
      #pragma unroll
      for (int i = 0; i < 2; ++i){
        int am = wm + 16*i + lr;
        af[i]  = *(const short8v*)(Al + am*64 + (((4*kk + g) ^ (am & 7))*8));
        int bn = wn + 16*i + lr;
        bfr[i] = *(const short8v*)(Bl + bn*64 + (((4*kk + g) ^ (bn & 7))*8));
      }
      acc[0][0] = mfma16(af[0], bfr[0], acc[0][0]);
      acc[0][1] = mfma16(af[0], bfr[1], acc[0][1]);
      acc[1][0] = mfma16(af[1], bfr[0], acc[1][0]);
      acc[1][1] = mfma16(af[1], bfr[1], acc[1][1]);
    }
    __syncthreads();
  }

  #pragma unroll
  for (int mi = 0; mi < 2; ++mi){
    #pragma unroll
    for (int ni = 0; ni < 2; ++ni){
      int colbase = col0 + wn + 16*ni;
      int col = colbase + lr;
      if (VSPLIT && colbase >= 512){
        int row = row0 + wm + 16*mi + 4*g;
        u32 lo = packbf(acc[mi][ni][0], acc[mi][ni][1]);
        u32 hi = packbf(acc[mi][ni][2], acc[mi][ni][3]);
        *(uint2v*)(vtg + (size_t)(col - 512)*NTOT + row) = (uint2v){lo, hi};
      } else {
        float bv = BIAS ? bias[col] : 0.f;
        #pragma unroll
        for (int j = 0; j < 4; ++j){
          int row = row0 + wm + 16*mi + 4*g + j;
          float v = acc[mi][ni][j] + bv;
          if (RELU) v = fmaxf(v, 0.f);
          if (BF16OUT) ((u16*)Cv)[(size_t)row*Nc + col] = f2bu(v);
          else         ((float*)Cv)[(size_t)row*Nc + col] = v;
        }
      }
    }
  }
}

// ---------------- MFMA flash attention, split-K x2, barrier-free, V prefetched ----------------
__global__ __launch_bounds__(256) void k_attn_mfma(const u16* __restrict__ qbf,
                                                   const u16* __restrict__ vtg,
                                                   u16* __restrict__ op,
                                                   float* __restrict__ mbuf, float* __restrict__ lbuf){
  __shared__ u16 Pl[4][16*64];               // per-wave P — no cross-wave sharing
  const int h   = blockIdx.y;
  const int ks  = blockIdx.z;
  const int qb  = blockIdx.x * 64;
  const int tid = threadIdx.x;
  const int w   = tid >> 6;
  const int l   = tid & 63;
  const int lr  = l & 15;
  const int g   = l >> 4;
  const float SC  = 0.17677669529663687f;    // 1/sqrt(32)
  const float SCL = 0.25503837f;             // SC * log2(e)
  const float DEFER = 31.368f;               // 8/SCL — P bounded by 2^8
  u16* opart = op + (size_t)ks*NTOT*DIM;

  short8v qf = *(const short8v*)(qbf + (size_t)(qb + 16*w + lr)*768 + h*DHD + 8*g);
  short8v ones;
  #pragma unroll
  for (int j = 0; j < 8; ++j) ones[j] = (short)0x3F80;

  float4v oa0 = {0.f,0.f,0.f,0.f}, oa1 = {0.f,0.f,0.f,0.f};
  float4v accl = {0.f,0.f,0.f,0.f};
  float mrun = -1e30f;
  u16* pw = &Pl[w][0];

  const u16* kp  = qbf + (size_t)(ks*KVQ + lr)*768 + 256 + h*DHD + 8*g;
  const u16* vb0 = vtg + (size_t)(h*DHD + lr)*NTOT + ks*KVQ + 8*g;        // dh = lr
  const u16* vb1 = vb0 + (size_t)16*NTOT;                                  // dh = lr+16
  short8v kf0 = *(const short8v*)(kp);
  short8v kf1 = *(const short8v*)(kp + (size_t)16*768);
  short8v kf2 = *(const short8v*)(kp + (size_t)32*768);
  short8v kf3 = *(const short8v*)(kp + (size_t)48*768);
  short8v vf00 = *(const short8v*)(vb0);          // kk=0, dh-block 0
  short8v vf01 = *(const short8v*)(vb0 + 32);     // kk=1, dh-block 0
  short8v vf10 = *(const short8v*)(vb1);          // kk=0, dh-block 1
  short8v vf11 = *(const short8v*)(vb1 + 32);     // kk=1, dh-block 1

  const int NIT = KVQ/64;
  for (int t = 0; t < NIT; ++t){
    // ---- S^T = K·Q ----
    float4v s0 = mfma16(kf0, qf, (float4v){0.f,0.f,0.f,0.f});
    float4v s1 = mfma16(kf1, qf, (float4v){0.f,0.f,0.f,0.f});
    float4v s2 = mfma16(kf2, qf, (float4v){0.f,0.f,0.f,0.f});
    float4v s3 = mfma16(kf3, qf, (float4v){0.f,0.f,0.f,0.f});
    // prefetch K (t+1); branchless (overread bounded inside ws)
    kp += (size_t)64*768;
    kf0 = *(const short8v*)(kp);
    kf1 = *(const short8v*)(kp + (size_t)16*768);
    kf2 = *(const short8v*)(kp + (size_t)32*768);
    kf3 = *(const short8v*)(kp + (size_t)48*768);

    // ---- per-lane softmax (q = lr) ----
    float m0 = fmaxf(fmaxf(fmaxf(s0[0],s0[1]),s0[2]),s0[3]);
    float m1 = fmaxf(fmaxf(fmaxf(s1[0],s1[1]),s1[2]),s1[3]);
    float m2 = fmaxf(fmaxf(fmaxf(s2[0],s2[1]),s2[2]),s2[3]);
    float m3 = fmaxf(fmaxf(fmaxf(s3[0],s3[1]),s3[2]),s3[3]);
    float tm = fmaxf(fmaxf(fmaxf(m0,m1),m2),m3);
    tm = fmaxf(tm, __shfl_xor(tm, 16));
    tm = fmaxf(tm, __shfl_xor(tm, 32));
    const bool nomax = __all(tm <= mrun + DEFER);
    float fac = 1.f;
    if (!nomax){
      float mn = fmaxf(mrun, tm);
      fac = exp2f((mrun - mn)*SCL);
      mrun = mn;
    }
    float mns = mrun*SCL;
    #pragma unroll
    for (int j = 0; j < 4; ++j){
      s0[j] = exp2f(__builtin_fmaf(s0[j], SCL, -mns));
      s1[j] = exp2f(__builtin_fmaf(s1[j], SCL, -mns));
      s2[j] = exp2f(__builtin_fmaf(s2[j], SCL, -mns));
      s3[j] = exp2f(__builtin_fmaf(s3[j], SCL, -mns));
    }

    // ---- P -> per-wave LDS (truncation-pack, b64, octet^lr swizzle) ----
    {
      int gh = g >> 1, gl = 4*(g & 1);
      uint2v* d0 = (uint2v*)(pw + lr*64 + ((0 + gh) ^ (lr & 7))*8 + gl);
      uint2v* d1 = (uint2v*)(pw + lr*64 + ((2 + gh) ^ (lr & 7))*8 + gl);
      uint2v* d2 = (uint2v*)(pw + lr*64 + ((4 + gh) ^ (lr & 7))*8 + gl);
      uint2v* d3 = (uint2v*)(pw + lr*64 + ((6 + gh) ^ (lr & 7))*8 + gl);
      *d0 = (uint2v){packbf(s0[0],s0[1]), packbf(s0[2],s0[3])};
      *d1 = (uint2v){packbf(s1[0],s1[1]), packbf(s1[2],s1[3])};
      *d2 = (uint2v){packbf(s2[0],s2[1]), packbf(s2[2],s2[3])};
      *d3 = (uint2v){packbf(s3[0],s3[1]), packbf(s3[2],s3[3])};
    }

    // ---- rescale (lane-local) ----
    if (!nomax){
      oa0[0]*=fac; oa0[1]*=fac; oa0[2]*=fac; oa0[3]*=fac;
      oa1[0]*=fac; oa1[1]*=fac; oa1[2]*=fac; oa1[3]*=fac;
      accl[0]*=fac; accl[1]*=fac; accl[2]*=fac; accl[3]*=fac;
    }

    // ---- O^T += V^T P^T; l += 1·P (V frags already in regs) ----
    {
      int slotp0 = (0 + g) ^ (lr & 7);
      int slotp1 = (4 + g) ^ (lr & 7);
      short8v pa0 = *(const short8v*)(pw + lr*64 + slotp0*8);
      short8v pa1 = *(const short8v*)(pw + lr*64 + slotp1*8);
      oa0  = mfma16(vf00, pa0, oa0);
      oa1  = mfma16(vf10, pa0, oa1);
      accl = mfma16(ones, pa0, accl);
      oa0  = mfma16(vf01, pa1, oa0);
      oa1  = mfma16(vf11, pa1, oa1);
      accl = mfma16(ones, pa1, accl);
    }
    // ---- prefetch V (t+1); latency hidden by next iter's QK^T+softmax ----
    vb0 += 64; vb1 += 64;
    vf00 = *(const short8v*)(vb0);
    vf01 = *(const short8v*)(vb0 + 32);
    vf10 = *(const short8v*)(vb1);
    vf11 = *(const short8v*)(vb1 + 32);
  }

  // ---- epilogue: packed bf16 partials (O[q=lr][dh=4g+j]) + m/l ----
  {
    size_t row = (size_t)(qb + 16*w + lr);
    u32 a0 = packbf(oa0[0], oa0[1]), a1 = packbf(oa0[2], oa0[3]);
    u32 b0 = packbf(oa1[0], oa1[1]), b1 = packbf(oa1[2], oa1[3]);
    *(uint2v*)(opart + row*DIM + h*DHD + 4*g)      = (uint2v){a0, a1};
    *(uint2v*)(opart + row*DIM + h*DHD + 16 + 4*g) = (uint2v){b0, b1};
  }
  if (g == 0){
    size_t mi = (size_t)(ks*NH + h)*NTOT + qb + 16*w + lr;
    mbuf[mi] = mrun*SC;
    lbuf[mi] = accl[0];
  }
}

// ---------------- split-K merge (2-way) ----------------
__global__ __launch_bounds__(256) void k_attn_merge(const u16* __restrict__ op,
                                                    const float* __restrict__ mbuf, const float* __restrict__ lbuf,
                                                    u16* __restrict__ obf){
  int i = blockIdx.x*256 + threadIdx.x;
  int r = i >> 8, c = i & 255, h = c >> 5;
  float m[KSPLIT], wgt[KSPLIT];
  float M = -1e30f;
  #pragma unroll
  for (int k = 0; k < KSPLIT; ++k){
    m[k] = mbuf[(size_t)(k*NH + h)*NTOT + r];
    M = fmaxf(M, m[k]);
  }
  float L = 0.f, acc = 0.f;
  #pragma unroll
  for (int k = 0; k < KSPLIT; ++k){
    wgt[k] = __expf(m[k] - M);
    L   += wgt[k]*lbuf[(size_t)(k*NH + h)*NTOT + r];
    acc += wgt[k]*bu2f(op[(size_t)k*NTOT*DIM + i]);
  }
  obf[i] = f2bu(acc / L);
}

// ---------------- fused residual + LayerNorm (+bf16 shadow) ----------------
template<int DUAL>
__global__ __launch_bounds__(256) void k_add_ln(const float* __restrict__ a, const float* __restrict__ b,
                                                const float* __restrict__ g, const float* __restrict__ be,
                                                float* __restrict__ out, u16* __restrict__ out2){
  __shared__ float red[4];
  int r = blockIdx.x, c = threadIdx.x;
  float v = a[((size_t)r << 8) + c] + b[((size_t)r << 8) + c];
  float s = v;
  #pragma unroll
  for (int off = 32; off; off >>= 1) s += __shfl_down(s, off);
  if ((c & 63) == 0) red[c >> 6] = s;
  __syncthreads();
  float mean = (red[0]+red[1]+red[2]+red[3]) * (1.f/DIM);
  __syncthreads();
  float d = v - mean;
  float s2 = d*d;
  #pragma unroll
  for (int off = 32; off; off >>= 1) s2 += __shfl_down(s2, off);
  if ((c & 63) == 0) red[c >> 6] = s2;
  __syncthreads();
  float var = (red[0]+red[1]+red[2]+red[3]) * (1.f/DIM);
  float rv = d * rsqrtf(var + LNEPS) * g[c] + be[c];
  out[((size_t)r << 8) + c] = rv;
  if (DUAL) out2[((size_t)r << 8) + c] = f2bu(rv);
}

// ---------------- fused LN2 + update (+final output copy) ----------------
template<int FINAL>
__global__ __launch_bounds__(256) void k_add_ln_upd(const float* __restrict__ a, const float* __restrict__ b,
                                                    const float* __restrict__ g, const float* __restrict__ be,
                                                    float* __restrict__ cur, float* __restrict__ tot,
                                                    float* __restrict__ out){
  __shared__ float red[4];
  int r = blockIdx.x, c = threadIdx.x;
  size_t idx = ((size_t)r << 8) + c;
  float v = a[idx] + b[idx];
  float s = v;
  #pragma unroll
  for (int off = 32; off; off >>= 1) s += __shfl_down(s, off);
  if ((c & 63) == 0) red[c >> 6] = s;
  __syncthreads();
  float mean = (red[0]+red[1]+red[2]+red[3]) * (1.f/DIM);
  __syncthreads();
  float d = v - mean;
  float s2 = d*d;
  #pragma unroll
  for (int off = 32; off; off >>= 1) s2 += __shfl_down(s2, off);
  if ((c & 63) == 0) red[c >> 6] = s2;
  __syncthreads();
  float var = (red[0]+red[1]+red[2]+red[3]) * (1.f/DIM);
  float rv = d * rsqrtf(var + LNEPS) * g[c] + be[c];
  float cu = cur[idx] + rv;
  cur[idx] = cu;
  float tv = tot[idx] + cu;
  tot[idx] = tv;
  if (FINAL){
    out[idx] = tv;
    out[(size_t)NTOT*DIM + idx] = tv;
  }
}

extern "C" void kernel_launch(void* const* d_in, const int* in_sizes, int n_in,
                              void* d_out, int out_size, void* d_ws, size_t ws_size,
                              hipStream_t stream){
  const int*   adj_row = (const int*)  d_in[0];
  const int*   adj_col = (const int*)  d_in[1];
  const float* adj_val = (const float*)d_in[2];
  const float* pe   = (const float*)d_in[3];
  const float* ae   = (const float*)d_in[4];
  const float* qe   = (const float*)d_in[5];
  const float* Wqkv = (const float*)d_in[6];
  const float* Wo   = (const float*)d_in[7];
  const float* W1   = (const float*)d_in[8];
  const float* b1   = (const float*)d_in[9];
  const float* W2   = (const float*)d_in[10];
  const float* b2   = (const float*)d_in[11];
  const float* g1   = (const float*)d_in[12];
  const float* be1  = (const float*)d_in[13];
  const float* g2   = (const float*)d_in[14];
  const float* be2  = (const float*)d_in[15];
  float* out = (float*)d_out;

  // ---- workspace (~36.7 MB, layout unchanged; vtg aliases obf) ----
  char* w = (char*)d_ws;
  float* cur  = (float*)w; w += (size_t)NTOT*DIM*4;
  float* tot  = (float*)w; w += (size_t)NTOT*DIM*4;
  float* tf   = (float*)w; w += (size_t)NTOT*DIM*4;
  float* pbuf = (float*)w; w += (size_t)NTOT*DIM*4;        // proj/ffn2 out; attn partials (2x bf16)
  float* x1   = (float*)w; w += (size_t)NTOT*DIM*4;
  u16* tbf    = (u16*)w;   w += (size_t)NTOT*DIM*2;        // spmm bf16; attn m/l
  u16* obf    = (u16*)w;   w += (size_t)NTOT*DIM*2;        // merge out; ALSO vtg (V^T) during attn
  u16* x1b    = (u16*)w;   w += (size_t)NTOT*DIM*2;
  u16* hq     = (u16*)w;   w += (size_t)NTOT*FFD*2;        // qbf ∪ h
  u16* wqkvt  = (u16*)w;   w += (size_t)768*256*2;
  u16* wot    = (u16*)w;   w += (size_t)256*256*2;
  u16* w1t    = (u16*)w;   w += (size_t)1024*256*2;
  u16* w2t    = (u16*)w;   w += (size_t)256*1024*2;
  int* rowptr = (int*)w;   w += (size_t)(NTOT+1)*4;
  int* cnt    = (int*)w;   w += (size_t)NTOT*4;
  int* cursor = (int*)w;   w += (size_t)NTOT*4;
  int* ccol   = (int*)w;   w += (size_t)NEDGE*4;
  float* cval = (float*)w; w += (size_t)NEDGE*4;
  u16* qbf  = hq;
  u16* vtg  = obf;                             // V^T [256][4096] bf16 = 2 MB
  u16* opbf = (u16*)pbuf;                      // 2 bf16 partials = 4 MB
  float* mbuf = (float*)tbf;                   // [KSPLIT][NH][NTOT] f32
  float* lbuf = mbuf + (size_t)KSPLIT*NH*NTOT;

  k_zero<<<16, 256, 0, stream>>>(cnt, NTOT);
  k_embed<<<NTOT, 256, 0, stream>>>(pe, ae, qe, cur, tot);
  k_hist<<<NEDGE/256, 256, 0, stream>>>(adj_row, cnt);
  k_scan<<<1, 64, 0, stream>>>(cnt, rowptr, cursor);
  k_scatter<<<NEDGE/256, 256, 0, stream>>>(adj_row, adj_col, adj_val, cursor, ccol, cval);
  k_wconv_all<<<2304, 256, 0, stream>>>(Wqkv, Wo, W1, W2, wqkvt, wot, w1t, w2t);

  for (int blk = 0; blk < 3; ++blk){
    k_spmm<<<NTOT, 256, 0, stream>>>(rowptr, ccol, cval, cur, tf, tbf);
    k_gemm64<0,0,1,1><<<dim3(768/64, NTOT/64), 256, 0, stream>>>(tbf, wqkvt, nullptr, qbf, vtg, NTOT, 256, 768);
    k_attn_mfma<<<dim3(NTOT/64, NH, KSPLIT), 256, 0, stream>>>(qbf, vtg, opbf, mbuf, lbuf);
    k_attn_merge<<<NTOT*DIM/256, 256, 0, stream>>>(opbf, mbuf, lbuf, obf);
    k_gemm64<0,0,0,0><<<dim3(256/64, NTOT/64), 256, 0, stream>>>(obf, wot, nullptr, pbuf, nullptr, NTOT, 256, 256);
    k_add_ln<1><<<NTOT, 256, 0, stream>>>(tf, pbuf, g1, be1, x1, x1b);
    k_gemm64<1,1,1,0><<<dim3(1024/64, NTOT/64), 256, 0, stream>>>(x1b, w1t, b1, hq, nullptr, NTOT, 256, 1024);
    k_gemm64<0,1,0,0><<<dim3(256/64, NTOT/64), 256, 0, stream>>>(hq, w2t, b2, pbuf, nullptr, NTOT, 1024, 256);
    if (blk < 2)
      k_add_ln_upd<0><<<NTOT, 256, 0, stream>>>(x1, pbuf, g2, be2, cur, tot, nullptr);
    else
      k_add_ln_upd<1><<<NTOT, 256, 0, stream>>>(x1, pbuf, g2, be2, cur, tot, out);
  }
}

// Round 18
// 473.235 us; speedup vs baseline: 1.3266x; 1.3208x over previous
//
#include <hip/hip_runtime.h>
#include <hip/hip_bf16.h>

// ProteinGNNTransformer — round 18: revert to r15 attention (barrier-free/global-V
// line abandoned per r16/r17 evidence: 128us vs r15's 81us). One new fusion:
// split-K merge folded into the proj GEMM's A-staging (merge had a single
// consumer; octets never cross head boundaries, so per-octet m/l combine is
// ~10 VALU) — removes 3 dispatches + a 6MB round-trip per launch.

#define NPROT 3000
#define NAA   25
#define NPROP 1071
#define NTOT  4096
#define DIM   256
#define NH    8
#define DHD   32
#define FFD   1024
#define NEDGE 131072
#define LNEPS 1e-5f
#define KSPLIT 2
#define KVQ (NTOT/KSPLIT)

typedef unsigned short u16;
typedef unsigned int u32;
typedef __attribute__((ext_vector_type(8))) short short8v;
typedef __attribute__((ext_vector_type(4))) float float4v;
typedef __attribute__((ext_vector_type(2))) unsigned int uint2v;

__device__ __forceinline__ u16 f2bu(float x){
  union { __hip_bfloat16 h; u16 u; } c; c.h = __float2bfloat16(x); return c.u;
}
__device__ __forceinline__ float bu2f(u16 u){
  union { u32 i; float f; } c; c.i = ((u32)u) << 16; return c.f;
}
__device__ __forceinline__ float4v mfma16(short8v a, short8v b, float4v c){
  return __builtin_amdgcn_mfma_f32_16x16x32_bf16(a, b, c, 0, 0, 0);
}
// pack two f32 to two bf16 (truncation) — v_perm idiom
__device__ __forceinline__ u32 packbf(float lo, float hi){
  u32 ul = __builtin_bit_cast(u32, lo);
  u32 uh = __builtin_bit_cast(u32, hi);
  return (ul >> 16) | (uh & 0xFFFF0000u);
}

// ---------------- embedding concat ----------------
__global__ __launch_bounds__(256) void k_embed(const float* __restrict__ pe, const float* __restrict__ ae,
                                               const float* __restrict__ qe,
                                               float* __restrict__ cur, float* __restrict__ tot){
  int i = blockIdx.x*256 + threadIdx.x;
  int row = i >> 8;
  float v;
  if (row < NPROT)           v = pe[i];
  else if (row < NPROT+NAA)  v = ae[i - NPROT*DIM];
  else                       v = qe[i - (NPROT+NAA)*DIM];
  cur[i] = v; tot[i] = v;
}

__global__ __launch_bounds__(256) void k_zero(int* __restrict__ p, int n){
  int i = blockIdx.x*256 + threadIdx.x; if (i < n) p[i] = 0;
}

// ---------------- fused weight transpose+convert ----------------
__global__ __launch_bounds__(256) void k_wconv_all(const float* __restrict__ Wqkv, const float* __restrict__ Wo,
                                                   const float* __restrict__ W1, const float* __restrict__ W2,
                                                   u16* __restrict__ wqkvt, u16* __restrict__ wot,
                                                   u16* __restrict__ w1t, u16* __restrict__ w2t){
  int b = blockIdx.x;
  const float* W; u16* Wt; int K, N, n;
  if (b < 768)       { W = Wqkv; Wt = wqkvt; K = 256;  N = 768;  n = b; }
  else if (b < 1024) { W = Wo;   Wt = wot;   K = 256;  N = 256;  n = b - 768; }
  else if (b < 2048) { W = W1;   Wt = w1t;   K = 256;  N = 1024; n = b - 1024; }
  else               { W = W2;   Wt = w2t;   K = 1024; N = 256;  n = b - 2048; }
  for (int k = threadIdx.x; k < K; k += 256)
    Wt[(size_t)n*K + k] = f2bu(W[(size_t)k*N + n]);
}

// ---------------- CSR build ----------------
__global__ __launch_bounds__(256) void k_hist(const int* __restrict__ rows, int* __restrict__ cnt){
  int e = blockIdx.x*256 + threadIdx.x; if (e < NEDGE) atomicAdd(&cnt[rows[e]], 1);
}

__global__ __launch_bounds__(64) void k_scan(const int* __restrict__ cnt, int* __restrict__ rowptr,
                                             int* __restrict__ cursor){
  int lane = threadIdx.x;
  int sum = 0;
  for (int i = 0; i < 64; ++i) sum += cnt[lane*64 + i];
  int pref = sum;
  #pragma unroll
  for (int off = 1; off < 64; off <<= 1){
    int u = __shfl_up(pref, off);
    if (lane >= off) pref += u;
  }
  int run = pref - sum;
  for (int i = 0; i < 64; ++i){
    int c = cnt[lane*64 + i];
    rowptr[lane*64 + i] = run;
    cursor[lane*64 + i] = run;
    run += c;
  }
  if (lane == 63) rowptr[NTOT] = run;
}

__global__ __launch_bounds__(256) void k_scatter(const int* __restrict__ rows, const int* __restrict__ cols,
                                                 const float* __restrict__ vals, int* __restrict__ cursor,
                                                 int* __restrict__ ccol, float* __restrict__ cval){
  int e = blockIdx.x*256 + threadIdx.x; if (e >= NEDGE) return;
  int p = atomicAdd(&cursor[rows[e]], 1);
  ccol[p] = cols[e]; cval[p] = vals[e];
}

// ---------------- SpMM: f32 out + bf16 shadow ----------------
__global__ __launch_bounds__(256) void k_spmm(const int* __restrict__ rowptr, const int* __restrict__ ccol,
                                              const float* __restrict__ cval, const float* __restrict__ x,
                                              float* __restrict__ out, u16* __restrict__ outb){
  int r = blockIdx.x, c = threadIdx.x;
  int s = rowptr[r], e = rowptr[r+1];
  float acc = 0.f;
  for (int i = s; i < e; ++i)
    acc += cval[i] * x[((size_t)ccol[i] << 8) + c];
  out[((size_t)r << 8) + c] = acc;
  outb[((size_t)r << 8) + c] = f2bu(acc);
}

// ---------------- MFMA GEMM, 64x64 tile; MERGE fuses split-K attn merge into A-staging ----------------
template<int RELU, int BIAS, int BF16OUT, int MERGE>
__global__ __launch_bounds__(256) void k_gemm64(const u16* __restrict__ A, const u16* __restrict__ Wt,
                                                const float* __restrict__ bias, void* __restrict__ Cv,
                                                const float* __restrict__ mbuf, const float* __restrict__ lbuf,
                                                int M, int K, int Nc){
  __shared__ u16 Al[64*64];
  __shared__ u16 Bl[64*64];
  const int tid = threadIdx.x;
  const int w  = tid >> 6, l = tid & 63, lr = l & 15, g = l >> 4;
  const int row0 = blockIdx.y*64, col0 = blockIdx.x*64;
  const int wm = (w >> 1)*32, wn = (w & 1)*32;
  const int sm = tid >> 2;
  const int so = (tid & 3)*2;
  float4v acc[2][2] = {};

  for (int k0 = 0; k0 < K; k0 += 64){
    const u16* Bs = Wt + (size_t)(col0 + sm)*K + k0 + so*8;
    if (MERGE){
      int row = row0 + sm;
      #pragma unroll
      for (int j = 0; j < 2; ++j){
        int o = so + j;
        int kabs = k0 + o*8;                 // octet lies within a single head
        int h = kabs >> 5;
        float mm0 = mbuf[(size_t)h*NTOT + row];
        float mm1 = mbuf[(size_t)(NH + h)*NTOT + row];
        float Mx = fmaxf(mm0, mm1);
        float e0 = __expf(mm0 - Mx), e1 = __expf(mm1 - Mx);
        float L = e0*lbuf[(size_t)h*NTOT + row] + e1*lbuf[(size_t)(NH + h)*NTOT + row];
        float sc0 = e0 / L, sc1 = e1 / L;
        short8v p0 = *(const short8v*)(A + (size_t)row*DIM + kabs);
        short8v p1 = *(const short8v*)(A + (size_t)NTOT*DIM + (size_t)row*DIM + kabs);
        short8v mv;
        #pragma unroll
        for (int jj = 0; jj < 8; ++jj)
          mv[jj] = (short)f2bu(sc0*bu2f((u16)p0[jj]) + sc1*bu2f((u16)p1[jj]));
        int slot = o ^ (sm & 7);
        *(short8v*)(Al + sm*64 + slot*8) = mv;
        *(short8v*)(Bl + sm*64 + slot*8) = *(const short8v*)(Bs + j*8);
      }
    } else {
      const u16* As = A + (size_t)(row0 + sm)*K + k0 + so*8;
      #pragma unroll
      for (int j = 0; j < 2; ++j){
        int o = so + j;
        int slot = o ^ (sm & 7);
        *(short8v*)(Al + sm*64 + slot*8) = *(const short8v*)(As + j*8);
        *(short8v*)(Bl + sm*64 + slot*8) = *(const short8v*)(Bs + j*8);
      }
    }
    __syncthreads();
    #pragma unroll
    for (int kk = 0; kk < 2; ++kk){
      short8v af[2], bfr[2];
      #pragma unroll
      for (int i = 0; i < 2; ++i){
        int am = wm + 16*i + lr;
        af[i]  = *(const short8v*)(Al + am*64 + (((4*kk + g) ^ (am & 7))*8));
        int bn = wn + 16*i + lr;
        bfr[i] = *(const short8v*)(Bl + bn*64 + (((4*kk + g) ^ (bn & 7))*8));
      }
      acc[0][0] = mfma16(af[0], bfr[0], acc[0][0]);
      acc[0][1] = mfma16(af[0], bfr[1], acc[0][1]);
      acc[1][0] = mfma16(af[1], bfr[0], acc[1][0]);
      acc[1][1] = mfma16(af[1], bfr[1], acc[1][1]);
    }
    __syncthreads();
  }

  #pragma unroll
  for (int mi = 0; mi < 2; ++mi){
    #pragma unroll
    for (int ni = 0; ni < 2; ++ni){
      int col = col0 + wn + 16*ni + lr;
      float bv = BIAS ? bias[col] : 0.f;
      #pragma unroll
      for (int j = 0; j < 4; ++j){
        int row = row0 + wm + 16*mi + 4*g + j;
        float v = acc[mi][ni][j] + bv;
        if (RELU) v = fmaxf(v, 0.f);
        if (BF16OUT) ((u16*)Cv)[(size_t)row*Nc + col] = f2bu(v);
        else         ((float*)Cv)[(size_t)row*Nc + col] = v;
      }
    }
  }
}

// ---------------- MFMA flash attention, split-K x2 (r15 structure, proven 81us) ----------------
__global__ __launch_bounds__(256) void k_attn_mfma(const u16* __restrict__ qbf,
                                                   u16* __restrict__ op,
                                                   float* __restrict__ mbuf, float* __restrict__ lbuf){
  __shared__ u16 Vt[2][32*64];
  __shared__ u16 Pl[4][16*64];
  __shared__ float Fl[4][16];
  const int h   = blockIdx.y;
  const int ks  = blockIdx.z;
  const int qb  = blockIdx.x * 64;
  const int tid = threadIdx.x;
  const int w   = tid >> 6;
  const int l   = tid & 63;
  const int lr  = l & 15;
  const int g   = l >> 4;
  const int sr  = tid >> 2;
  const int sq  = tid & 3;
  const float SC  = 0.17677669529663687f;          // 1/sqrt(32)
  const float SCL = 0.25503837f;                    // SC * log2(e)
  const float DEFER = 31.368f;                      // 8/SCL: P bounded by 2^8
  u16* opart = op + (size_t)ks*NTOT*DIM;

  short8v qf = *(const short8v*)(qbf + (size_t)(qb + 16*w + lr)*768 + h*DHD + 8*g);
  short8v ones;
  #pragma unroll
  for (int j = 0; j < 8; ++j) ones[j] = (short)0x3F80;   // bf16 1.0

  float4v oa0 = {0.f,0.f,0.f,0.f}, oa1 = {0.f,0.f,0.f,0.f};
  float4v accl = {0.f,0.f,0.f,0.f};                 // row-sums (same D-domain as oa)
  float mrun = -1e30f;                              // per-lane (q = lr), raw domain
  u16* pw = &Pl[w][0];

  const u16* vp = qbf + (size_t)(ks*KVQ + sr)*768 + 512 + h*DHD + 8*sq;
  const u16* kp = qbf + (size_t)(ks*KVQ + lr)*768 + 256 + h*DHD + 8*g;
  short8v vreg = *(const short8v*)vp;
  short8v kf0 = *(const short8v*)(kp);
  short8v kf1 = *(const short8v*)(kp + (size_t)16*768);
  short8v kf2 = *(const short8v*)(kp + (size_t)32*768);
  short8v kf3 = *(const short8v*)(kp + (size_t)48*768);

  const int NIT = KVQ/64;
  for (int t = 0; t < NIT; ++t){
    u16* vt = &Vt[t & 1][0];
    #pragma unroll
    for (int j = 0; j < 8; ++j){
      int row  = 8*sq + j;
      int slot = (sr >> 3) ^ j;
      vt[row*64 + slot*8 + (sr & 7)] = (u16)vreg[j];
    }
    __syncthreads();
    vp += (size_t)64*768;
    if (t + 1 < NIT) vreg = *(const short8v*)vp;

    float4v s0 = mfma16(kf0, qf, (float4v){0.f,0.f,0.f,0.f});
    float4v s1 = mfma16(kf1, qf, (float4v){0.f,0.f,0.f,0.f});
    float4v s2 = mfma16(kf2, qf, (float4v){0.f,0.f,0.f,0.f});
    float4v s3 = mfma16(kf3, qf, (float4v){0.f,0.f,0.f,0.f});
    if (t + 1 < NIT){
      const u16* kn = kp + (size_t)(t+1)*64*768;
      kf0 = *(const short8v*)(kn);
      kf1 = *(const short8v*)(kn + (size_t)16*768);
      kf2 = *(const short8v*)(kn + (size_t)32*768);
      kf3 = *(const short8v*)(kn + (size_t)48*768);
    }

    // ---- tile max (max3-friendly chains) ----
    float m0 = fmaxf(fmaxf(fmaxf(s0[0],s0[1]),s0[2]),s0[3]);
    float m1 = fmaxf(fmaxf(fmaxf(s1[0],s1[1]),s1[2]),s1[3]);
    float m2 = fmaxf(fmaxf(fmaxf(s2[0],s2[1]),s2[2]),s2[3]);
    float m3 = fmaxf(fmaxf(fmaxf(s3[0],s3[1]),s3[2]),s3[3]);
    float tm = fmaxf(fmaxf(fmaxf(m0,m1),m2),m3);
    tm = fmaxf(tm, __shfl_xor(tm, 16));
    tm = fmaxf(tm, __shfl_xor(tm, 32));
    const bool nomax = __all(tm <= mrun + DEFER);
    float fac = 1.f;
    if (!nomax){
      float mn = fmaxf(mrun, tm);
      fac = exp2f((mrun - mn)*SCL);
      mrun = mn;
    }
    float mns = mrun*SCL;
    #pragma unroll
    for (int j = 0; j < 4; ++j){
      s0[j] = exp2f(__builtin_fmaf(s0[j], SCL, -mns));
      s1[j] = exp2f(__builtin_fmaf(s1[j], SCL, -mns));
      s2[j] = exp2f(__builtin_fmaf(s2[j], SCL, -mns));
      s3[j] = exp2f(__builtin_fmaf(s3[j], SCL, -mns));
    }

    // ---- P -> LDS: truncation-pack + b64 writes ----
    {
      int gh = g >> 1, gl = 4*(g & 1);
      uint2v* d0 = (uint2v*)(pw + lr*64 + ((0 + gh) ^ (lr & 7))*8 + gl);
      uint2v* d1 = (uint2v*)(pw + lr*64 + ((2 + gh) ^ (lr & 7))*8 + gl);
      uint2v* d2 = (uint2v*)(pw + lr*64 + ((4 + gh) ^ (lr & 7))*8 + gl);
      uint2v* d3 = (uint2v*)(pw + lr*64 + ((6 + gh) ^ (lr & 7))*8 + gl);
      *d0 = (uint2v){packbf(s0[0],s0[1]), packbf(s0[2],s0[3])};
      *d1 = (uint2v){packbf(s1[0],s1[1]), packbf(s1[2],s1[3])};
      *d2 = (uint2v){packbf(s2[0],s2[1]), packbf(s2[2],s2[3])};
      *d3 = (uint2v){packbf(s3[0],s3[1]), packbf(s3[2],s3[3])};
    }

    if (!nomax){
      if (g == 0) Fl[w][lr] = fac;
      float fq0 = Fl[w][4*g+0], fq1 = Fl[w][4*g+1], fq2 = Fl[w][4*g+2], fq3 = Fl[w][4*g+3];
      oa0[0]*=fq0; oa0[1]*=fq1; oa0[2]*=fq2; oa0[3]*=fq3;
      oa1[0]*=fq0; oa1[1]*=fq1; oa1[2]*=fq2; oa1[3]*=fq3;
      accl[0]*=fq0; accl[1]*=fq1; accl[2]*=fq2; accl[3]*=fq3;
    }

    // ---- O += P V; l += P 1 ----
    #pragma unroll
    for (int kk = 0; kk < 2; ++kk){
      int slotp = (4*kk + g) ^ (lr & 7);
      short8v pa = *(const short8v*)(pw + lr*64 + slotp*8);
      short8v v0 = *(const short8v*)(vt + lr*64        + slotp*8);
      short8v v1 = *(const short8v*)(vt + (lr+16)*64   + slotp*8);
      oa0  = mfma16(pa, v0, oa0);
      oa1  = mfma16(pa, v1, oa1);
      accl = mfma16(pa, ones, accl);
    }
  }

  // ---- epilogue: bf16 unnormalized partials + scaled m + l ----
  #pragma unroll
  for (int j = 0; j < 4; ++j){
    size_t row = (size_t)(qb + 16*w + 4*g + j);
    opart[row*DIM + h*DHD + lr]      = f2bu(oa0[j]);
    opart[row*DIM + h*DHD + 16 + lr] = f2bu(oa1[j]);
  }
  if (l < 16){
    size_t mi = (size_t)(ks*NH + h)*NTOT + qb + 16*w + lr;
    mbuf[mi] = mrun*SC;
  }
  if (lr == 0){
    #pragma unroll
    for (int j = 0; j < 4; ++j){
      size_t mi = (size_t)(ks*NH + h)*NTOT + qb + 16*w + 4*g + j;
      lbuf[mi] = accl[j];
    }
  }
}

// ---------------- fused residual + LayerNorm (+bf16 shadow) ----------------
template<int DUAL>
__global__ __launch_bounds__(256) void k_add_ln(const float* __restrict__ a, const float* __restrict__ b,
                                                const float* __restrict__ g, const float* __restrict__ be,
                                                float* __restrict__ out, u16* __restrict__ out2){
  __shared__ float red[4];
  int r = blockIdx.x, c = threadIdx.x;
  float v = a[((size_t)r << 8) + c] + b[((size_t)r << 8) + c];
  float s = v;
  #pragma unroll
  for (int off = 32; off; off >>= 1) s += __shfl_down(s, off);
  if ((c & 63) == 0) red[c >> 6] = s;
  __syncthreads();
  float mean = (red[0]+red[1]+red[2]+red[3]) * (1.f/DIM);
  __syncthreads();
  float d = v - mean;
  float s2 = d*d;
  #pragma unroll
  for (int off = 32; off; off >>= 1) s2 += __shfl_down(s2, off);
  if ((c & 63) == 0) red[c >> 6] = s2;
  __syncthreads();
  float var = (red[0]+red[1]+red[2]+red[3]) * (1.f/DIM);
  float rv = d * rsqrtf(var + LNEPS) * g[c] + be[c];
  out[((size_t)r << 8) + c] = rv;
  if (DUAL) out2[((size_t)r << 8) + c] = f2bu(rv);
}

// ---------------- fused LN2 + update (+final output copy) ----------------
template<int FINAL>
__global__ __launch_bounds__(256) void k_add_ln_upd(const float* __restrict__ a, const float* __restrict__ b,
                                                    const float* __restrict__ g, const float* __restrict__ be,
                                                    float* __restrict__ cur, float* __restrict__ tot,
                                                    float* __restrict__ out){
  __shared__ float red[4];
  int r = blockIdx.x, c = threadIdx.x;
  size_t idx = ((size_t)r << 8) + c;
  float v = a[idx] + b[idx];
  float s = v;
  #pragma unroll
  for (int off = 32; off; off >>= 1) s += __shfl_down(s, off);
  if ((c & 63) == 0) red[c >> 6] = s;
  __syncthreads();
  float mean = (red[0]+red[1]+red[2]+red[3]) * (1.f/DIM);
  __syncthreads();
  float d = v - mean;
  float s2 = d*d;
  #pragma unroll
  for (int off = 32; off; off >>= 1) s2 += __shfl_down(s2, off);
  if ((c & 63) == 0) red[c >> 6] = s2;
  __syncthreads();
  float var = (red[0]+red[1]+red[2]+red[3]) * (1.f/DIM);
  float rv = d * rsqrtf(var + LNEPS) * g[c] + be[c];
  float cu = cur[idx] + rv;
  cur[idx] = cu;
  float tv = tot[idx] + cu;
  tot[idx] = tv;
  if (FINAL){
    out[idx] = tv;
    out[(size_t)NTOT*DIM + idx] = tv;
  }
}

extern "C" void kernel_launch(void* const* d_in, const int* in_sizes, int n_in,
                              void* d_out, int out_size, void* d_ws, size_t ws_size,
                              hipStream_t stream){
  const int*   adj_row = (const int*)  d_in[0];
  const int*   adj_col = (const int*)  d_in[1];
  const float* adj_val = (const float*)d_in[2];
  const float* pe   = (const float*)d_in[3];
  const float* ae   = (const float*)d_in[4];
  const float* qe   = (const float*)d_in[5];
  const float* Wqkv = (const float*)d_in[6];
  const float* Wo   = (const float*)d_in[7];
  const float* W1   = (const float*)d_in[8];
  const float* b1   = (const float*)d_in[9];
  const float* W2   = (const float*)d_in[10];
  const float* b2   = (const float*)d_in[11];
  const float* g1   = (const float*)d_in[12];
  const float* be1  = (const float*)d_in[13];
  const float* g2   = (const float*)d_in[14];
  const float* be2  = (const float*)d_in[15];
  float* out = (float*)d_out;

  // ---- workspace (~36.7 MB, layout unchanged) ----
  char* w = (char*)d_ws;
  float* cur  = (float*)w; w += (size_t)NTOT*DIM*4;
  float* tot  = (float*)w; w += (size_t)NTOT*DIM*4;
  float* tf   = (float*)w; w += (size_t)NTOT*DIM*4;
  float* pbuf = (float*)w; w += (size_t)NTOT*DIM*4;        // proj/ffn2 out; attn partials (2x bf16)
  float* x1   = (float*)w; w += (size_t)NTOT*DIM*4;
  u16* tbf    = (u16*)w;   w += (size_t)NTOT*DIM*2;        // spmm bf16; attn m/l
  u16* obf    = (u16*)w;   w += (size_t)NTOT*DIM*2;        // (unused this round)
  u16* x1b    = (u16*)w;   w += (size_t)NTOT*DIM*2;
  u16* hq     = (u16*)w;   w += (size_t)NTOT*FFD*2;        // qbf ∪ h
  u16* wqkvt  = (u16*)w;   w += (size_t)768*256*2;
  u16* wot    = (u16*)w;   w += (size_t)256*256*2;
  u16* w1t    = (u16*)w;   w += (size_t)1024*256*2;
  u16* w2t    = (u16*)w;   w += (size_t)256*1024*2;
  int* rowptr = (int*)w;   w += (size_t)(NTOT+1)*4;
  int* cnt    = (int*)w;   w += (size_t)NTOT*4;
  int* cursor = (int*)w;   w += (size_t)NTOT*4;
  int* ccol   = (int*)w;   w += (size_t)NEDGE*4;
  float* cval = (float*)w; w += (size_t)NEDGE*4;
  u16* qbf  = hq;
  u16* opbf = (u16*)pbuf;                      // 2 bf16 partials = 4 MB (pbuf region)
  float* mbuf = (float*)tbf;                   // [KSPLIT][NH][NTOT] f32 (256 KB)
  float* lbuf = mbuf + (size_t)KSPLIT*NH*NTOT; // 256 KB (inside dead tbf)

  k_zero<<<16, 256, 0, stream>>>(cnt, NTOT);
  k_embed<<<NTOT, 256, 0, stream>>>(pe, ae, qe, cur, tot);
  k_hist<<<NEDGE/256, 256, 0, stream>>>(adj_row, cnt);
  k_scan<<<1, 64, 0, stream>>>(cnt, rowptr, cursor);
  k_scatter<<<NEDGE/256, 256, 0, stream>>>(adj_row, adj_col, adj_val, cursor, ccol, cval);
  k_wconv_all<<<2304, 256, 0, stream>>>(Wqkv, Wo, W1, W2, wqkvt, wot, w1t, w2t);

  for (int blk = 0; blk < 3; ++blk){
    k_spmm<<<NTOT, 256, 0, stream>>>(rowptr, ccol, cval, cur, tf, tbf);
    k_gemm64<0,0,1,0><<<dim3(768/64, NTOT/64), 256, 0, stream>>>(tbf, wqkvt, nullptr, qbf, nullptr, nullptr, NTOT, 256, 768);
    k_attn_mfma<<<dim3(NTOT/64, NH, KSPLIT), 256, 0, stream>>>(qbf, opbf, mbuf, lbuf);
    // proj GEMM with fused split-K merge (reads partials + m/l directly)
    k_gemm64<0,0,0,1><<<dim3(256/64, NTOT/64), 256, 0, stream>>>(opbf, wot, nullptr, pbuf, mbuf, lbuf, NTOT, 256, 256);
    k_add_ln<1><<<NTOT, 256, 0, stream>>>(tf, pbuf, g1, be1, x1, x1b);
    k_gemm64<1,1,1,0><<<dim3(1024/64, NTOT/64), 256, 0, stream>>>(x1b, w1t, b1, hq, nullptr, nullptr, NTOT, 256, 1024);
    k_gemm64<0,1,0,0><<<dim3(256/64, NTOT/64), 256, 0, stream>>>(hq, w2t, b2, pbuf, nullptr, nullptr, NTOT, 1024, 256);
    if (blk < 2)
      k_add_ln_upd<0><<<NTOT, 256, 0, stream>>>(x1, pbuf, g2, be2, cur, tot, nullptr);
    else
      k_add_ln_upd<1><<<NTOT, 256, 0, stream>>>(x1, pbuf, g2, be2, cur, tot, out);
  }
}

// Round 19
// 471.392 us; speedup vs baseline: 1.3318x; 1.0039x over previous
//
#include <hip/hip_runtime.h>
#include <hip/hip_bf16.h>

// ProteinGNNTransformer — round 19: r18 + (1) bf16 shadow of `cur` for SpMM
// gather (halves SpMM's ~130MB L2 traffic; shadow lives in the dead obf
// region), (2) branchless K/V prefetch in attention (overread stays inside
// the 8MB hq region for both split halves).

#define NPROT 3000
#define NAA   25
#define NPROP 1071
#define NTOT  4096
#define DIM   256
#define NH    8
#define DHD   32
#define FFD   1024
#define NEDGE 131072
#define LNEPS 1e-5f
#define KSPLIT 2
#define KVQ (NTOT/KSPLIT)

typedef unsigned short u16;
typedef unsigned int u32;
typedef __attribute__((ext_vector_type(8))) short short8v;
typedef __attribute__((ext_vector_type(4))) float float4v;
typedef __attribute__((ext_vector_type(2))) unsigned int uint2v;

__device__ __forceinline__ u16 f2bu(float x){
  union { __hip_bfloat16 h; u16 u; } c; c.h = __float2bfloat16(x); return c.u;
}
__device__ __forceinline__ float bu2f(u16 u){
  union { u32 i; float f; } c; c.i = ((u32)u) << 16; return c.f;
}
__device__ __forceinline__ float4v mfma16(short8v a, short8v b, float4v c){
  return __builtin_amdgcn_mfma_f32_16x16x32_bf16(a, b, c, 0, 0, 0);
}
// pack two f32 to two bf16 (truncation) — v_perm idiom
__device__ __forceinline__ u32 packbf(float lo, float hi){
  u32 ul = __builtin_bit_cast(u32, lo);
  u32 uh = __builtin_bit_cast(u32, hi);
  return (ul >> 16) | (uh & 0xFFFF0000u);
}

// ---------------- embedding concat (+bf16 shadow of cur) ----------------
__global__ __launch_bounds__(256) void k_embed(const float* __restrict__ pe, const float* __restrict__ ae,
                                               const float* __restrict__ qe,
                                               float* __restrict__ cur, float* __restrict__ tot,
                                               u16* __restrict__ curb){
  int i = blockIdx.x*256 + threadIdx.x;
  int row = i >> 8;
  float v;
  if (row < NPROT)           v = pe[i];
  else if (row < NPROT+NAA)  v = ae[i - NPROT*DIM];
  else                       v = qe[i - (NPROT+NAA)*DIM];
  cur[i] = v; tot[i] = v; curb[i] = f2bu(v);
}

__global__ __launch_bounds__(256) void k_zero(int* __restrict__ p, int n){
  int i = blockIdx.x*256 + threadIdx.x; if (i < n) p[i] = 0;
}

// ---------------- fused weight transpose+convert ----------------
__global__ __launch_bounds__(256) void k_wconv_all(const float* __restrict__ Wqkv, const float* __restrict__ Wo,
                                                   const float* __restrict__ W1, const float* __restrict__ W2,
                                                   u16* __restrict__ wqkvt, u16* __restrict__ wot,
                                                   u16* __restrict__ w1t, u16* __restrict__ w2t){
  int b = blockIdx.x;
  const float* W; u16* Wt; int K, N, n;
  if (b < 768)       { W = Wqkv; Wt = wqkvt; K = 256;  N = 768;  n = b; }
  else if (b < 1024) { W = Wo;   Wt = wot;   K = 256;  N = 256;  n = b - 768; }
  else if (b < 2048) { W = W1;   Wt = w1t;   K = 256;  N = 1024; n = b - 1024; }
  else               { W = W2;   Wt = w2t;   K = 1024; N = 256;  n = b - 2048; }
  for (int k = threadIdx.x; k < K; k += 256)
    Wt[(size_t)n*K + k] = f2bu(W[(size_t)k*N + n]);
}

// ---------------- CSR build ----------------
__global__ __launch_bounds__(256) void k_hist(const int* __restrict__ rows, int* __restrict__ cnt){
  int e = blockIdx.x*256 + threadIdx.x; if (e < NEDGE) atomicAdd(&cnt[rows[e]], 1);
}

__global__ __launch_bounds__(64) void k_scan(const int* __restrict__ cnt, int* __restrict__ rowptr,
                                             int* __restrict__ cursor){
  int lane = threadIdx.x;
  int sum = 0;
  for (int i = 0; i < 64; ++i) sum += cnt[lane*64 + i];
  int pref = sum;
  #pragma unroll
  for (int off = 1; off < 64; off <<= 1){
    int u = __shfl_up(pref, off);
    if (lane >= off) pref += u;
  }
  int run = pref - sum;
  for (int i = 0; i < 64; ++i){
    int c = cnt[lane*64 + i];
    rowptr[lane*64 + i] = run;
    cursor[lane*64 + i] = run;
    run += c;
  }
  if (lane == 63) rowptr[NTOT] = run;
}

__global__ __launch_bounds__(256) void k_scatter(const int* __restrict__ rows, const int* __restrict__ cols,
                                                 const float* __restrict__ vals, int* __restrict__ cursor,
                                                 int* __restrict__ ccol, float* __restrict__ cval){
  int e = blockIdx.x*256 + threadIdx.x; if (e >= NEDGE) return;
  int p = atomicAdd(&cursor[rows[e]], 1);
  ccol[p] = cols[e]; cval[p] = vals[e];
}

// ---------------- SpMM (bf16 gather): f32 out + bf16 shadow ----------------
__global__ __launch_bounds__(256) void k_spmm(const int* __restrict__ rowptr, const int* __restrict__ ccol,
                                              const float* __restrict__ cval, const u16* __restrict__ xb,
                                              float* __restrict__ out, u16* __restrict__ outb){
  int r = blockIdx.x, c = threadIdx.x;
  int s = rowptr[r], e = rowptr[r+1];
  float acc = 0.f;
  for (int i = s; i < e; ++i)
    acc += cval[i] * bu2f(xb[((size_t)ccol[i] << 8) + c]);
  out[((size_t)r << 8) + c] = acc;
  outb[((size_t)r << 8) + c] = f2bu(acc);
}

// ---------------- MFMA GEMM, 64x64 tile; MERGE fuses split-K attn merge ----------------
template<int RELU, int BIAS, int BF16OUT, int MERGE>
__global__ __launch_bounds__(256) void k_gemm64(const u16* __restrict__ A, const u16* __restrict__ Wt,
                                                const float* __restrict__ bias, void* __restrict__ Cv,
                                                const float* __restrict__ mbuf, const float* __restrict__ lbuf,
                                                int M, int K, int Nc){
  __shared__ u16 Al[64*64];
  __shared__ u16 Bl[64*64];
  const int tid = threadIdx.x;
  const int w  = tid >> 6, l = tid & 63, lr = l & 15, g = l >> 4;
  const int row0 = blockIdx.y*64, col0 = blockIdx.x*64;
  const int wm = (w >> 1)*32, wn = (w & 1)*32;
  const int sm = tid >> 2;
  const int so = (tid & 3)*2;
  float4v acc[2][2] = {};

  for (int k0 = 0; k0 < K; k0 += 64){
    const u16* Bs = Wt + (size_t)(col0 + sm)*K + k0 + so*8;
    if (MERGE){
      int row = row0 + sm;
      #pragma unroll
      for (int j = 0; j < 2; ++j){
        int o = so + j;
        int kabs = k0 + o*8;                 // octet lies within a single head
        int h = kabs >> 5;
        float mm0 = mbuf[(size_t)h*NTOT + row];
        float mm1 = mbuf[(size_t)(NH + h)*NTOT + row];
        float Mx = fmaxf(mm0, mm1);
        float e0 = __expf(mm0 - Mx), e1 = __expf(mm1 - Mx);
        float L = e0*lbuf[(size_t)h*NTOT + row] + e1*lbuf[(size_t)(NH + h)*NTOT + row];
        float sc0 = e0 / L, sc1 = e1 / L;
        short8v p0 = *(const short8v*)(A + (size_t)row*DIM + kabs);
        short8v p1 = *(const short8v*)(A + (size_t)NTOT*DIM + (size_t)row*DIM + kabs);
        short8v mv;
        #pragma unroll
        for (int jj = 0; jj < 8; ++jj)
          mv[jj] = (short)f2bu(sc0*bu2f((u16)p0[jj]) + sc1*bu2f((u16)p1[jj]));
        int slot = o ^ (sm & 7);
        *(short8v*)(Al + sm*64 + slot*8) = mv;
        *(short8v*)(Bl + sm*64 + slot*8) = *(const short8v*)(Bs + j*8);
      }
    } else {
      const u16* As = A + (size_t)(row0 + sm)*K + k0 + so*8;
      #pragma unroll
      for (int j = 0; j < 2; ++j){
        int o = so + j;
        int slot = o ^ (sm & 7);
        *(short8v*)(Al + sm*64 + slot*8) = *(const short8v*)(As + j*8);
        *(short8v*)(Bl + sm*64 + slot*8) = *(const short8v*)(Bs + j*8);
      }
    }
    __syncthreads();
    #pragma unroll
    for (int kk = 0; kk < 2; ++kk){
      short8v af[2], bfr[2];
      #pragma unroll
      for (int i = 0; i < 2; ++i){
        int am = wm + 16*i + lr;
        af[i]  = *(const short8v*)(Al + am*64 + (((4*kk + g) ^ (am & 7))*8));
        int bn = wn + 16*i + lr;
        bfr[i] = *(const short8v*)(Bl + bn*64 + (((4*kk + g) ^ (bn & 7))*8));
      }
      acc[0][0] = mfma16(af[0], bfr[0], acc[0][0]);
      acc[0][1] = mfma16(af[0], bfr[1], acc[0][1]);
      acc[1][0] = mfma16(af[1], bfr[0], acc[1][0]);
      acc[1][1] = mfma16(af[1], bfr[1], acc[1][1]);
    }
    __syncthreads();
  }

  #pragma unroll
  for (int mi = 0; mi < 2; ++mi){
    #pragma unroll
    for (int ni = 0; ni < 2; ++ni){
      int col = col0 + wn + 16*ni + lr;
      float bv = BIAS ? bias[col] : 0.f;
      #pragma unroll
      for (int j = 0; j < 4; ++j){
        int row = row0 + wm + 16*mi + 4*g + j;
        float v = acc[mi][ni][j] + bv;
        if (RELU) v = fmaxf(v, 0.f);
        if (BF16OUT) ((u16*)Cv)[(size_t)row*Nc + col] = f2bu(v);
        else         ((float*)Cv)[(size_t)row*Nc + col] = v;
      }
    }
  }
}

// ---------------- MFMA flash attention, split-K x2 (r15 structure, branchless prefetch) ----------------
__global__ __launch_bounds__(256) void k_attn_mfma(const u16* __restrict__ qbf,
                                                   u16* __restrict__ op,
                                                   float* __restrict__ mbuf, float* __restrict__ lbuf){
  __shared__ u16 Vt[2][32*64];
  __shared__ u16 Pl[4][16*64];
  __shared__ float Fl[4][16];
  const int h   = blockIdx.y;
  const int ks  = blockIdx.z;
  const int qb  = blockIdx.x * 64;
  const int tid = threadIdx.x;
  const int w   = tid >> 6;
  const int l   = tid & 63;
  const int lr  = l & 15;
  const int g   = l >> 4;
  const int sr  = tid >> 2;
  const int sq  = tid & 3;
  const float SC  = 0.17677669529663687f;          // 1/sqrt(32)
  const float SCL = 0.25503837f;                    // SC * log2(e)
  const float DEFER = 31.368f;                      // 8/SCL: P bounded by 2^8
  u16* opart = op + (size_t)ks*NTOT*DIM;

  short8v qf = *(const short8v*)(qbf + (size_t)(qb + 16*w + lr)*768 + h*DHD + 8*g);
  short8v ones;
  #pragma unroll
  for (int j = 0; j < 8; ++j) ones[j] = (short)0x3F80;   // bf16 1.0

  float4v oa0 = {0.f,0.f,0.f,0.f}, oa1 = {0.f,0.f,0.f,0.f};
  float4v accl = {0.f,0.f,0.f,0.f};
  float mrun = -1e30f;
  u16* pw = &Pl[w][0];

  // branchless prefetch: t+1 overread (<= row 4159) stays inside the 8MB hq region
  const u16* vp = qbf + (size_t)(ks*KVQ + sr)*768 + 512 + h*DHD + 8*sq;
  const u16* kp = qbf + (size_t)(ks*KVQ + lr)*768 + 256 + h*DHD + 8*g;
  short8v vreg = *(const short8v*)vp;
  short8v kf0 = *(const short8v*)(kp);
  short8v kf1 = *(const short8v*)(kp + (size_t)16*768);
  short8v kf2 = *(const short8v*)(kp + (size_t)32*768);
  short8v kf3 = *(const short8v*)(kp + (size_t)48*768);

  const int NIT = KVQ/64;
  for (int t = 0; t < NIT; ++t){
    u16* vt = &Vt[t & 1][0];
    #pragma unroll
    for (int j = 0; j < 8; ++j){
      int row  = 8*sq + j;
      int slot = (sr >> 3) ^ j;
      vt[row*64 + slot*8 + (sr & 7)] = (u16)vreg[j];
    }
    __syncthreads();
    vp += (size_t)64*768;
    vreg = *(const short8v*)vp;

    float4v s0 = mfma16(kf0, qf, (float4v){0.f,0.f,0.f,0.f});
    float4v s1 = mfma16(kf1, qf, (float4v){0.f,0.f,0.f,0.f});
    float4v s2 = mfma16(kf2, qf, (float4v){0.f,0.f,0.f,0.f});
    float4v s3 = mfma16(kf3, qf, (float4v){0.f,0.f,0.f,0.f});
    kp += (size_t)64*768;
    kf0 = *(const short8v*)(kp);
    kf1 = *(const short8v*)(kp + (size_t)16*768);
    kf2 = *(const short8v*)(kp + (size_t)32*768);
    kf3 = *(const short8v*)(kp + (size_t)48*768);

    // ---- tile max (max3-friendly chains) ----
    float m0 = fmaxf(fmaxf(fmaxf(s0[0],s0[1]),s0[2]),s0[3]);
    float m1 = fmaxf(fmaxf(fmaxf(s1[0],s1[1]),s1[2]),s1[3]);
    float m2 = fmaxf(fmaxf(fmaxf(s2[0],s2[1]),s2[2]),s2[3]);
    float m3 = fmaxf(fmaxf(fmaxf(s3[0],s3[1]),s3[2]),s3[3]);
    float tm = fmaxf(fmaxf(fmaxf(m0,m1),m2),m3);
    tm = fmaxf(tm, __shfl_xor(tm, 16));
    tm = fmaxf(tm, __shfl_xor(tm, 32));
    const bool nomax = __all(tm <= mrun + DEFER);
    float fac = 1.f;
    if (!nomax){
      float mn = fmaxf(mrun, tm);
      fac = exp2f((mrun - mn)*SCL);
      mrun = mn;
    }
    float mns = mrun*SCL;
    #pragma unroll
    for (int j = 0; j < 4; ++j){
      s0[j] = exp2f(__builtin_fmaf(s0[j], SCL, -mns));
      s1[j] = exp2f(__builtin_fmaf(s1[j], SCL, -mns));
      s2[j] = exp2f(__builtin_fmaf(s2[j], SCL, -mns));
      s3[j] = exp2f(__builtin_fmaf(s3[j], SCL, -mns));
    }

    // ---- P -> LDS: truncation-pack + b64 writes ----
    {
      int gh = g >> 1, gl = 4*(g & 1);
      uint2v* d0 = (uint2v*)(pw + lr*64 + ((0 + gh) ^ (lr & 7))*8 + gl);
      uint2v* d1 = (uint2v*)(pw + lr*64 + ((2 + gh) ^ (lr & 7))*8 + gl);
      uint2v* d2 = (uint2v*)(pw + lr*64 + ((4 + gh) ^ (lr & 7))*8 + gl);
      uint2v* d3 = (uint2v*)(pw + lr*64 + ((6 + gh) ^ (lr & 7))*8 + gl);
      *d0 = (uint2v){packbf(s0[0],s0[1]), packbf(s0[2],s0[3])};
      *d1 = (uint2v){packbf(s1[0],s1[1]), packbf(s1[2],s1[3])};
      *d2 = (uint2v){packbf(s2[0],s2[1]), packbf(s2[2],s2[3])};
      *d3 = (uint2v){packbf(s3[0],s3[1]), packbf(s3[2],s3[3])};
    }

    if (!nomax){
      if (g == 0) Fl[w][lr] = fac;
      float fq0 = Fl[w][4*g+0], fq1 = Fl[w][4*g+1], fq2 = Fl[w][4*g+2], fq3 = Fl[w][4*g+3];
      oa0[0]*=fq0; oa0[1]*=fq1; oa0[2]*=fq2; oa0[3]*=fq3;
      oa1[0]*=fq0; oa1[1]*=fq1; oa1[2]*=fq2; oa1[3]*=fq3;
      accl[0]*=fq0; accl[1]*=fq1; accl[2]*=fq2; accl[3]*=fq3;
    }

    // ---- O += P V; l += P 1 ----
    #pragma unroll
    for (int kk = 0; kk < 2; ++kk){
      int slotp = (4*kk + g) ^ (lr & 7);
      short8v pa = *(const short8v*)(pw + lr*64 + slotp*8);
      short8v v0 = *(const short8v*)(vt + lr*64        + slotp*8);
      short8v v1 = *(const short8v*)(vt + (lr+16)*64   + slotp*8);
      oa0  = mfma16(pa, v0, oa0);
      oa1  = mfma16(pa, v1, oa1);
      accl = mfma16(pa, ones, accl);
    }
  }

  // ---- epilogue: bf16 unnormalized partials + scaled m + l ----
  #pragma unroll
  for (int j = 0; j < 4; ++j){
    size_t row = (size_t)(qb + 16*w + 4*g + j);
    opart[row*DIM + h*DHD + lr]      = f2bu(oa0[j]);
    opart[row*DIM + h*DHD + 16 + lr] = f2bu(oa1[j]);
  }
  if (l < 16){
    size_t mi = (size_t)(ks*NH + h)*NTOT + qb + 16*w + lr;
    mbuf[mi] = mrun*SC;
  }
  if (lr == 0){
    #pragma unroll
    for (int j = 0; j < 4; ++j){
      size_t mi = (size_t)(ks*NH + h)*NTOT + qb + 16*w + 4*g + j;
      lbuf[mi] = accl[j];
    }
  }
}

// ---------------- fused residual + LayerNorm (+bf16 shadow) ----------------
template<int DUAL>
__global__ __launch_bounds__(256) void k_add_ln(const float* __restrict__ a, const float* __restrict__ b,
                                                const float* __restrict__ g, const float* __restrict__ be,
                                                float* __restrict__ out, u16* __restrict__ out2){
  __shared__ float red[4];
  int r = blockIdx.x, c = threadIdx.x;
  float v = a[((size_t)r << 8) + c] + b[((size_t)r << 8) + c];
  float s = v;
  #pragma unroll
  for (int off = 32; off; off >>= 1) s += __shfl_down(s, off);
  if ((c & 63) == 0) red[c >> 6] = s;
  __syncthreads();
  float mean = (red[0]+red[1]+red[2]+red[3]) * (1.f/DIM);
  __syncthreads();
  float d = v - mean;
  float s2 = d*d;
  #pragma unroll
  for (int off = 32; off; off >>= 1) s2 += __shfl_down(s2, off);
  if ((c & 63) == 0) red[c >> 6] = s2;
  __syncthreads();
  float var = (red[0]+red[1]+red[2]+red[3]) * (1.f/DIM);
  float rv = d * rsqrtf(var + LNEPS) * g[c] + be[c];
  out[((size_t)r << 8) + c] = rv;
  if (DUAL) out2[((size_t)r << 8) + c] = f2bu(rv);
}

// ---------------- fused LN2 + update (+bf16 cur shadow, +final output) ----------------
template<int FINAL>
__global__ __launch_bounds__(256) void k_add_ln_upd(const float* __restrict__ a, const float* __restrict__ b,
                                                    const float* __restrict__ g, const float* __restrict__ be,
                                                    float* __restrict__ cur, float* __restrict__ tot,
                                                    u16* __restrict__ curb, float* __restrict__ out){
  __shared__ float red[4];
  int r = blockIdx.x, c = threadIdx.x;
  size_t idx = ((size_t)r << 8) + c;
  float v = a[idx] + b[idx];
  float s = v;
  #pragma unroll
  for (int off = 32; off; off >>= 1) s += __shfl_down(s, off);
  if ((c & 63) == 0) red[c >> 6] = s;
  __syncthreads();
  float mean = (red[0]+red[1]+red[2]+red[3]) * (1.f/DIM);
  __syncthreads();
  float d = v - mean;
  float s2 = d*d;
  #pragma unroll
  for (int off = 32; off; off >>= 1) s2 += __shfl_down(s2, off);
  if ((c & 63) == 0) red[c >> 6] = s2;
  __syncthreads();
  float var = (red[0]+red[1]+red[2]+red[3]) * (1.f/DIM);
  float rv = d * rsqrtf(var + LNEPS) * g[c] + be[c];
  float cu = cur[idx] + rv;
  cur[idx] = cu;
  if (!FINAL) curb[idx] = f2bu(cu);
  float tv = tot[idx] + cu;
  tot[idx] = tv;
  if (FINAL){
    out[idx] = tv;
    out[(size_t)NTOT*DIM + idx] = tv;
  }
}

extern "C" void kernel_launch(void* const* d_in, const int* in_sizes, int n_in,
                              void* d_out, int out_size, void* d_ws, size_t ws_size,
                              hipStream_t stream){
  const int*   adj_row = (const int*)  d_in[0];
  const int*   adj_col = (const int*)  d_in[1];
  const float* adj_val = (const float*)d_in[2];
  const float* pe   = (const float*)d_in[3];
  const float* ae   = (const float*)d_in[4];
  const float* qe   = (const float*)d_in[5];
  const float* Wqkv = (const float*)d_in[6];
  const float* Wo   = (const float*)d_in[7];
  const float* W1   = (const float*)d_in[8];
  const float* b1   = (const float*)d_in[9];
  const float* W2   = (const float*)d_in[10];
  const float* b2   = (const float*)d_in[11];
  const float* g1   = (const float*)d_in[12];
  const float* be1  = (const float*)d_in[13];
  const float* g2   = (const float*)d_in[14];
  const float* be2  = (const float*)d_in[15];
  float* out = (float*)d_out;

  // ---- workspace (~36.7 MB, layout unchanged) ----
  char* w = (char*)d_ws;
  float* cur  = (float*)w; w += (size_t)NTOT*DIM*4;
  float* tot  = (float*)w; w += (size_t)NTOT*DIM*4;
  float* tf   = (float*)w; w += (size_t)NTOT*DIM*4;
  float* pbuf = (float*)w; w += (size_t)NTOT*DIM*4;        // proj/ffn2 out; attn partials (2x bf16)
  float* x1   = (float*)w; w += (size_t)NTOT*DIM*4;
  u16* tbf    = (u16*)w;   w += (size_t)NTOT*DIM*2;        // spmm bf16; attn m/l
  u16* curb   = (u16*)w;   w += (size_t)NTOT*DIM*2;        // bf16 shadow of cur (ex-obf)
  u16* x1b    = (u16*)w;   w += (size_t)NTOT*DIM*2;
  u16* hq     = (u16*)w;   w += (size_t)NTOT*FFD*2;        // qbf ∪ h
  u16* wqkvt  = (u16*)w;   w += (size_t)768*256*2;
  u16* wot    = (u16*)w;   w += (size_t)256*256*2;
  u16* w1t    = (u16*)w;   w += (size_t)1024*256*2;
  u16* w2t    = (u16*)w;   w += (size_t)256*1024*2;
  int* rowptr = (int*)w;   w += (size_t)(NTOT+1)*4;
  int* cnt    = (int*)w;   w += (size_t)NTOT*4;
  int* cursor = (int*)w;   w += (size_t)NTOT*4;
  int* ccol   = (int*)w;   w += (size_t)NEDGE*4;
  float* cval = (float*)w; w += (size_t)NEDGE*4;
  u16* qbf  = hq;
  u16* opbf = (u16*)pbuf;                      // 2 bf16 partials = 4 MB (pbuf region)
  float* mbuf = (float*)tbf;                   // [KSPLIT][NH][NTOT] f32 (256 KB)
  float* lbuf = mbuf + (size_t)KSPLIT*NH*NTOT; // 256 KB (inside dead tbf)

  k_zero<<<16, 256, 0, stream>>>(cnt, NTOT);
  k_embed<<<NTOT, 256, 0, stream>>>(pe, ae, qe, cur, tot, curb);
  k_hist<<<NEDGE/256, 256, 0, stream>>>(adj_row, cnt);
  k_scan<<<1, 64, 0, stream>>>(cnt, rowptr, cursor);
  k_scatter<<<NEDGE/256, 256, 0, stream>>>(adj_row, adj_col, adj_val, cursor, ccol, cval);
  k_wconv_all<<<2304, 256, 0, stream>>>(Wqkv, Wo, W1, W2, wqkvt, wot, w1t, w2t);

  for (int blk = 0; blk < 3; ++blk){
    k_spmm<<<NTOT, 256, 0, stream>>>(rowptr, ccol, cval, curb, tf, tbf);
    k_gemm64<0,0,1,0><<<dim3(768/64, NTOT/64), 256, 0, stream>>>(tbf, wqkvt, nullptr, qbf, nullptr, nullptr, NTOT, 256, 768);
    k_attn_mfma<<<dim3(NTOT/64, NH, KSPLIT), 256, 0, stream>>>(qbf, opbf, mbuf, lbuf);
    k_gemm64<0,0,0,1><<<dim3(256/64, NTOT/64), 256, 0, stream>>>(opbf, wot, nullptr, pbuf, mbuf, lbuf, NTOT, 256, 256);
    k_add_ln<1><<<NTOT, 256, 0, stream>>>(tf, pbuf, g1, be1, x1, x1b);
    k_gemm64<1,1,1,0><<<dim3(1024/64, NTOT/64), 256, 0, stream>>>(x1b, w1t, b1, hq, nullptr, nullptr, NTOT, 256, 1024);
    k_gemm64<0,1,0,0><<<dim3(256/64, NTOT/64), 256, 0, stream>>>(hq, w2t, b2, pbuf, nullptr, nullptr, NTOT, 1024, 256);
    if (blk < 2)
      k_add_ln_upd<0><<<NTOT, 256, 0, stream>>>(x1, pbuf, g2, be2, cur, tot, curb, nullptr);
    else
      k_add_ln_upd<1><<<NTOT, 256, 0, stream>>>(x1, pbuf, g2, be2, cur, tot, nullptr, out);
  }
}

// Round 20
// 470.364 us; speedup vs baseline: 1.3347x; 1.0022x over previous
//
#include <hip/hip_runtime.h>
#include <hip/hip_bf16.h>

// ProteinGNNTransformer — round 20: GEMM staging via async global_load_lds
// (width 16) with pre-swizzled per-lane GLOBAL source + linear LDS dest
// (m173 pattern; o = (lane&7)^((lane>>3)&7) reproduces slot = o^(row&7)).
// MERGE (proj) path keeps reg-staging (needs combine math). Numerics-neutral.
// Everything else identical to r19 (471us baseline).

#define NPROT 3000
#define NAA   25
#define NPROP 1071
#define NTOT  4096
#define DIM   256
#define NH    8
#define DHD   32
#define FFD   1024
#define NEDGE 131072
#define LNEPS 1e-5f
#define KSPLIT 2
#define KVQ (NTOT/KSPLIT)

typedef unsigned short u16;
typedef unsigned int u32;
typedef __attribute__((ext_vector_type(8))) short short8v;
typedef __attribute__((ext_vector_type(4))) float float4v;
typedef __attribute__((ext_vector_type(2))) unsigned int uint2v;

__device__ __forceinline__ u16 f2bu(float x){
  union { __hip_bfloat16 h; u16 u; } c; c.h = __float2bfloat16(x); return c.u;
}
__device__ __forceinline__ float bu2f(u16 u){
  union { u32 i; float f; } c; c.i = ((u32)u) << 16; return c.f;
}
__device__ __forceinline__ float4v mfma16(short8v a, short8v b, float4v c){
  return __builtin_amdgcn_mfma_f32_16x16x32_bf16(a, b, c, 0, 0, 0);
}
// pack two f32 to two bf16 (truncation) — v_perm idiom
__device__ __forceinline__ u32 packbf(float lo, float hi){
  u32 ul = __builtin_bit_cast(u32, lo);
  u32 uh = __builtin_bit_cast(u32, hi);
  return (ul >> 16) | (uh & 0xFFFF0000u);
}
// async global->LDS, 16 bytes/lane (dest = wave-uniform base + lane*16)
__device__ __forceinline__ void gload_lds16(const u16* g, u16* l){
  __builtin_amdgcn_global_load_lds(
      (const __attribute__((address_space(1))) void*)g,
      (__attribute__((address_space(3))) void*)l, 16, 0, 0);
}

// ---------------- embedding concat (+bf16 shadow of cur) ----------------
__global__ __launch_bounds__(256) void k_embed(const float* __restrict__ pe, const float* __restrict__ ae,
                                               const float* __restrict__ qe,
                                               float* __restrict__ cur, float* __restrict__ tot,
                                               u16* __restrict__ curb){
  int i = blockIdx.x*256 + threadIdx.x;
  int row = i >> 8;
  float v;
  if (row < NPROT)           v = pe[i];
  else if (row < NPROT+NAA)  v = ae[i - NPROT*DIM];
  else                       v = qe[i - (NPROT+NAA)*DIM];
  cur[i] = v; tot[i] = v; curb[i] = f2bu(v);
}

__global__ __launch_bounds__(256) void k_zero(int* __restrict__ p, int n){
  int i = blockIdx.x*256 + threadIdx.x; if (i < n) p[i] = 0;
}

// ---------------- fused weight transpose+convert ----------------
__global__ __launch_bounds__(256) void k_wconv_all(const float* __restrict__ Wqkv, const float* __restrict__ Wo,
                                                   const float* __restrict__ W1, const float* __restrict__ W2,
                                                   u16* __restrict__ wqkvt, u16* __restrict__ wot,
                                                   u16* __restrict__ w1t, u16* __restrict__ w2t){
  int b = blockIdx.x;
  const float* W; u16* Wt; int K, N, n;
  if (b < 768)       { W = Wqkv; Wt = wqkvt; K = 256;  N = 768;  n = b; }
  else if (b < 1024) { W = Wo;   Wt = wot;   K = 256;  N = 256;  n = b - 768; }
  else if (b < 2048) { W = W1;   Wt = w1t;   K = 256;  N = 1024; n = b - 1024; }
  else               { W = W2;   Wt = w2t;   K = 1024; N = 256;  n = b - 2048; }
  for (int k = threadIdx.x; k < K; k += 256)
    Wt[(size_t)n*K + k] = f2bu(W[(size_t)k*N + n]);
}

// ---------------- CSR build ----------------
__global__ __launch_bounds__(256) void k_hist(const int* __restrict__ rows, int* __restrict__ cnt){
  int e = blockIdx.x*256 + threadIdx.x; if (e < NEDGE) atomicAdd(&cnt[rows[e]], 1);
}

__global__ __launch_bounds__(64) void k_scan(const int* __restrict__ cnt, int* __restrict__ rowptr,
                                             int* __restrict__ cursor){
  int lane = threadIdx.x;
  int sum = 0;
  for (int i = 0; i < 64; ++i) sum += cnt[lane*64 + i];
  int pref = sum;
  #pragma unroll
  for (int off = 1; off < 64; off <<= 1){
    int u = __shfl_up(pref, off);
    if (lane >= off) pref += u;
  }
  int run = pref - sum;
  for (int i = 0; i < 64; ++i){
    int c = cnt[lane*64 + i];
    rowptr[lane*64 + i] = run;
    cursor[lane*64 + i] = run;
    run += c;
  }
  if (lane == 63) rowptr[NTOT] = run;
}

__global__ __launch_bounds__(256) void k_scatter(const int* __restrict__ rows, const int* __restrict__ cols,
                                                 const float* __restrict__ vals, int* __restrict__ cursor,
                                                 int* __restrict__ ccol, float* __restrict__ cval){
  int e = blockIdx.x*256 + threadIdx.x; if (e >= NEDGE) return;
  int p = atomicAdd(&cursor[rows[e]], 1);
  ccol[p] = cols[e]; cval[p] = vals[e];
}

// ---------------- SpMM (bf16 gather): f32 out + bf16 shadow ----------------
__global__ __launch_bounds__(256) void k_spmm(const int* __restrict__ rowptr, const int* __restrict__ ccol,
                                              const float* __restrict__ cval, const u16* __restrict__ xb,
                                              float* __restrict__ out, u16* __restrict__ outb){
  int r = blockIdx.x, c = threadIdx.x;
  int s = rowptr[r], e = rowptr[r+1];
  float acc = 0.f;
  for (int i = s; i < e; ++i)
    acc += cval[i] * bu2f(xb[((size_t)ccol[i] << 8) + c]);
  out[((size_t)r << 8) + c] = acc;
  outb[((size_t)r << 8) + c] = f2bu(acc);
}

// ---------------- MFMA GEMM, 64x64 tile; async staging; MERGE fuses attn merge ----------------
template<int RELU, int BIAS, int BF16OUT, int MERGE>
__global__ __launch_bounds__(256) void k_gemm64(const u16* __restrict__ A, const u16* __restrict__ Wt,
                                                const float* __restrict__ bias, void* __restrict__ Cv,
                                                const float* __restrict__ mbuf, const float* __restrict__ lbuf,
                                                int M, int K, int Nc){
  __shared__ u16 Al[64*64];
  __shared__ u16 Bl[64*64];
  const int tid = threadIdx.x;
  const int w  = tid >> 6, l = tid & 63, lr = l & 15, g = l >> 4;
  const int row0 = blockIdx.y*64, col0 = blockIdx.x*64;
  const int wm = (w >> 1)*32, wn = (w & 1)*32;
  const int sm = tid >> 2;
  const int so = (tid & 3)*2;
  // async-staging lane geometry: wave w instr i covers rows [16w+8i, 16w+8i+8)
  const int srow = (l >> 3);                 // row within 8-row group
  const int soct = (l & 7) ^ srow;           // pre-swizzled global octet
  float4v acc[2][2] = {};

  for (int k0 = 0; k0 < K; k0 += 64){
    if (MERGE){
      const u16* Bs = Wt + (size_t)(col0 + sm)*K + k0 + so*8;
      int row = row0 + sm;
      #pragma unroll
      for (int j = 0; j < 2; ++j){
        int o = so + j;
        int kabs = k0 + o*8;                 // octet lies within a single head
        int h = kabs >> 5;
        float mm0 = mbuf[(size_t)h*NTOT + row];
        float mm1 = mbuf[(size_t)(NH + h)*NTOT + row];
        float Mx = fmaxf(mm0, mm1);
        float e0 = __expf(mm0 - Mx), e1 = __expf(mm1 - Mx);
        float L = e0*lbuf[(size_t)h*NTOT + row] + e1*lbuf[(size_t)(NH + h)*NTOT + row];
        float sc0 = e0 / L, sc1 = e1 / L;
        short8v p0 = *(const short8v*)(A + (size_t)row*DIM + kabs);
        short8v p1 = *(const short8v*)(A + (size_t)NTOT*DIM + (size_t)row*DIM + kabs);
        short8v mv;
        #pragma unroll
        for (int jj = 0; jj < 8; ++jj)
          mv[jj] = (short)f2bu(sc0*bu2f((u16)p0[jj]) + sc1*bu2f((u16)p1[jj]));
        int slot = o ^ (sm & 7);
        *(short8v*)(Al + sm*64 + slot*8) = mv;
        *(short8v*)(Bl + sm*64 + slot*8) = *(const short8v*)(Bs + j*8);
      }
    } else {
      // async global->LDS: linear LDS dest (wave base + lane*16B), swizzled global src
      #pragma unroll
      for (int i = 0; i < 2; ++i){
        int row = 16*w + 8*i + srow;
        gload_lds16(A  + (size_t)(row0 + row)*K + k0 + soct*8, Al + (16*w + 8*i)*64);
        gload_lds16(Wt + (size_t)(col0 + row)*K + k0 + soct*8, Bl + (16*w + 8*i)*64);
      }
    }
    __syncthreads();
    #pragma unroll
    for (int kk = 0; kk < 2; ++kk){
      short8v af[2], bfr[2];
      #pragma unroll
      for (int i = 0; i < 2; ++i){
        int am = wm + 16*i + lr;
        af[i]  = *(const short8v*)(Al + am*64 + (((4*kk + g) ^ (am & 7))*8));
        int bn = wn + 16*i + lr;
        bfr[i] = *(const short8v*)(Bl + bn*64 + (((4*kk + g) ^ (bn & 7))*8));
      }
      acc[0][0] = mfma16(af[0], bfr[0], acc[0][0]);
      acc[0][1] = mfma16(af[0], bfr[1], acc[0][1]);
      acc[1][0] = mfma16(af[1], bfr[0], acc[1][0]);
      acc[1][1] = mfma16(af[1], bfr[1], acc[1][1]);
    }
    __syncthreads();
  }

  #pragma unroll
  for (int mi = 0; mi < 2; ++mi){
    #pragma unroll
    for (int ni = 0; ni < 2; ++ni){
      int col = col0 + wn + 16*ni + lr;
      float bv = BIAS ? bias[col] : 0.f;
      #pragma unroll
      for (int j = 0; j < 4; ++j){
        int row = row0 + wm + 16*mi + 4*g + j;
        float v = acc[mi][ni][j] + bv;
        if (RELU) v = fmaxf(v, 0.f);
        if (BF16OUT) ((u16*)Cv)[(size_t)row*Nc + col] = f2bu(v);
        else         ((float*)Cv)[(size_t)row*Nc + col] = v;
      }
    }
  }
}

// ---------------- MFMA flash attention, split-K x2 (unchanged from r19) ----------------
__global__ __launch_bounds__(256) void k_attn_mfma(const u16* __restrict__ qbf,
                                                   u16* __restrict__ op,
                                                   float* __restrict__ mbuf, float* __restrict__ lbuf){
  __shared__ u16 Vt[2][32*64];
  __shared__ u16 Pl[4][16*64];
  __shared__ float Fl[4][16];
  const int h   = blockIdx.y;
  const int ks  = blockIdx.z;
  const int qb  = blockIdx.x * 64;
  const int tid = threadIdx.x;
  const int w   = tid >> 6;
  const int l   = tid & 63;
  const int lr  = l & 15;
  const int g   = l >> 4;
  const int sr  = tid >> 2;
  const int sq  = tid & 3;
  const float SC  = 0.17677669529663687f;          // 1/sqrt(32)
  const float SCL = 0.25503837f;                    // SC * log2(e)
  const float DEFER = 31.368f;                      // 8/SCL: P bounded by 2^8
  u16* opart = op + (size_t)ks*NTOT*DIM;

  short8v qf = *(const short8v*)(qbf + (size_t)(qb + 16*w + lr)*768 + h*DHD + 8*g);
  short8v ones;
  #pragma unroll
  for (int j = 0; j < 8; ++j) ones[j] = (short)0x3F80;   // bf16 1.0

  float4v oa0 = {0.f,0.f,0.f,0.f}, oa1 = {0.f,0.f,0.f,0.f};
  float4v accl = {0.f,0.f,0.f,0.f};
  float mrun = -1e30f;
  u16* pw = &Pl[w][0];

  const u16* vp = qbf + (size_t)(ks*KVQ + sr)*768 + 512 + h*DHD + 8*sq;
  const u16* kp = qbf + (size_t)(ks*KVQ + lr)*768 + 256 + h*DHD + 8*g;
  short8v vreg = *(const short8v*)vp;
  short8v kf0 = *(const short8v*)(kp);
  short8v kf1 = *(const short8v*)(kp + (size_t)16*768);
  short8v kf2 = *(const short8v*)(kp + (size_t)32*768);
  short8v kf3 = *(const short8v*)(kp + (size_t)48*768);

  const int NIT = KVQ/64;
  for (int t = 0; t < NIT; ++t){
    u16* vt = &Vt[t & 1][0];
    #pragma unroll
    for (int j = 0; j < 8; ++j){
      int row  = 8*sq + j;
      int slot = (sr >> 3) ^ j;
      vt[row*64 + slot*8 + (sr & 7)] = (u16)vreg[j];
    }
    __syncthreads();
    vp += (size_t)64*768;
    vreg = *(const short8v*)vp;

    float4v s0 = mfma16(kf0, qf, (float4v){0.f,0.f,0.f,0.f});
    float4v s1 = mfma16(kf1, qf, (float4v){0.f,0.f,0.f,0.f});
    float4v s2 = mfma16(kf2, qf, (float4v){0.f,0.f,0.f,0.f});
    float4v s3 = mfma16(kf3, qf, (float4v){0.f,0.f,0.f,0.f});
    kp += (size_t)64*768;
    kf0 = *(const short8v*)(kp);
    kf1 = *(const short8v*)(kp + (size_t)16*768);
    kf2 = *(const short8v*)(kp + (size_t)32*768);
    kf3 = *(const short8v*)(kp + (size_t)48*768);

    float m0 = fmaxf(fmaxf(fmaxf(s0[0],s0[1]),s0[2]),s0[3]);
    float m1 = fmaxf(fmaxf(fmaxf(s1[0],s1[1]),s1[2]),s1[3]);
    float m2 = fmaxf(fmaxf(fmaxf(s2[0],s2[1]),s2[2]),s2[3]);
    float m3 = fmaxf(fmaxf(fmaxf(s3[0],s3[1]),s3[2]),s3[3]);
    float tm = fmaxf(fmaxf(fmaxf(m0,m1),m2),m3);
    tm = fmaxf(tm, __shfl_xor(tm, 16));
    tm = fmaxf(tm, __shfl_xor(tm, 32));
    const bool nomax = __all(tm <= mrun + DEFER);
    float fac = 1.f;
    if (!nomax){
      float mn = fmaxf(mrun, tm);
      fac = exp2f((mrun - mn)*SCL);
      mrun = mn;
    }
    float mns = mrun*SCL;
    #pragma unroll
    for (int j = 0; j < 4; ++j){
      s0[j] = exp2f(__builtin_fmaf(s0[j], SCL, -mns));
      s1[j] = exp2f(__builtin_fmaf(s1[j], SCL, -mns));
      s2[j] = exp2f(__builtin_fmaf(s2[j], SCL, -mns));
      s3[j] = exp2f(__builtin_fmaf(s3[j], SCL, -mns));
    }

    {
      int gh = g >> 1, gl = 4*(g & 1);
      uint2v* d0 = (uint2v*)(pw + lr*64 + ((0 + gh) ^ (lr & 7))*8 + gl);
      uint2v* d1 = (uint2v*)(pw + lr*64 + ((2 + gh) ^ (lr & 7))*8 + gl);
      uint2v* d2 = (uint2v*)(pw + lr*64 + ((4 + gh) ^ (lr & 7))*8 + gl);
      uint2v* d3 = (uint2v*)(pw + lr*64 + ((6 + gh) ^ (lr & 7))*8 + gl);
      *d0 = (uint2v){packbf(s0[0],s0[1]), packbf(s0[2],s0[3])};
      *d1 = (uint2v){packbf(s1[0],s1[1]), packbf(s1[2],s1[3])};
      *d2 = (uint2v){packbf(s2[0],s2[1]), packbf(s2[2],s2[3])};
      *d3 = (uint2v){packbf(s3[0],s3[1]), packbf(s3[2],s3[3])};
    }

    if (!nomax){
      if (g == 0) Fl[w][lr] = fac;
      float fq0 = Fl[w][4*g+0], fq1 = Fl[w][4*g+1], fq2 = Fl[w][4*g+2], fq3 = Fl[w][4*g+3];
      oa0[0]*=fq0; oa0[1]*=fq1; oa0[2]*=fq2; oa0[3]*=fq3;
      oa1[0]*=fq0; oa1[1]*=fq1; oa1[2]*=fq2; oa1[3]*=fq3;
      accl[0]*=fq0; accl[1]*=fq1; accl[2]*=fq2; accl[3]*=fq3;
    }

    #pragma unroll
    for (int kk = 0; kk < 2; ++kk){
      int slotp = (4*kk + g) ^ (lr & 7);
      short8v pa = *(const short8v*)(pw + lr*64 + slotp*8);
      short8v v0 = *(const short8v*)(vt + lr*64        + slotp*8);
      short8v v1 = *(const short8v*)(vt + (lr+16)*64   + slotp*8);
      oa0  = mfma16(pa, v0, oa0);
      oa1  = mfma16(pa, v1, oa1);
      accl = mfma16(pa, ones, accl);
    }
  }

  #pragma unroll
  for (int j = 0; j < 4; ++j){
    size_t row = (size_t)(qb + 16*w + 4*g + j);
    opart[row*DIM + h*DHD + lr]      = f2bu(oa0[j]);
    opart[row*DIM + h*DHD + 16 + lr] = f2bu(oa1[j]);
  }
  if (l < 16){
    size_t mi = (size_t)(ks*NH + h)*NTOT + qb + 16*w + lr;
    mbuf[mi] = mrun*SC;
  }
  if (lr == 0){
    #pragma unroll
    for (int j = 0; j < 4; ++j){
      size_t mi = (size_t)(ks*NH + h)*NTOT + qb + 16*w + 4*g + j;
      lbuf[mi] = accl[j];
    }
  }
}

// ---------------- fused residual + LayerNorm (+bf16 shadow) ----------------
template<int DUAL>
__global__ __launch_bounds__(256) void k_add_ln(const float* __restrict__ a, const float* __restrict__ b,
                                                const float* __restrict__ g, const float* __restrict__ be,
                                                float* __restrict__ out, u16* __restrict__ out2){
  __shared__ float red[4];
  int r = blockIdx.x, c = threadIdx.x;
  float v = a[((size_t)r << 8) + c] + b[((size_t)r << 8) + c];
  float s = v;
  #pragma unroll
  for (int off = 32; off; off >>= 1) s += __shfl_down(s, off);
  if ((c & 63) == 0) red[c >> 6] = s;
  __syncthreads();
  float mean = (red[0]+red[1]+red[2]+red[3]) * (1.f/DIM);
  __syncthreads();
  float d = v - mean;
  float s2 = d*d;
  #pragma unroll
  for (int off = 32; off; off >>= 1) s2 += __shfl_down(s2, off);
  if ((c & 63) == 0) red[c >> 6] = s2;
  __syncthreads();
  float var = (red[0]+red[1]+red[2]+red[3]) * (1.f/DIM);
  float rv = d * rsqrtf(var + LNEPS) * g[c] + be[c];
  out[((size_t)r << 8) + c] = rv;
  if (DUAL) out2[((size_t)r << 8) + c] = f2bu(rv);
}

// ---------------- fused LN2 + update (+bf16 cur shadow, +final output) ----------------
template<int FINAL>
__global__ __launch_bounds__(256) void k_add_ln_upd(const float* __restrict__ a, const float* __restrict__ b,
                                                    const float* __restrict__ g, const float* __restrict__ be,
                                                    float* __restrict__ cur, float* __restrict__ tot,
                                                    u16* __restrict__ curb, float* __restrict__ out){
  __shared__ float red[4];
  int r = blockIdx.x, c = threadIdx.x;
  size_t idx = ((size_t)r << 8) + c;
  float v = a[idx] + b[idx];
  float s = v;
  #pragma unroll
  for (int off = 32; off; off >>= 1) s += __shfl_down(s, off);
  if ((c & 63) == 0) red[c >> 6] = s;
  __syncthreads();
  float mean = (red[0]+red[1]+red[2]+red[3]) * (1.f/DIM);
  __syncthreads();
  float d = v - mean;
  float s2 = d*d;
  #pragma unroll
  for (int off = 32; off; off >>= 1) s2 += __shfl_down(s2, off);
  if ((c & 63) == 0) red[c >> 6] = s2;
  __syncthreads();
  float var = (red[0]+red[1]+red[2]+red[3]) * (1.f/DIM);
  float rv = d * rsqrtf(var + LNEPS) * g[c] + be[c];
  float cu = cur[idx] + rv;
  cur[idx] = cu;
  if (!FINAL) curb[idx] = f2bu(cu);
  float tv = tot[idx] + cu;
  tot[idx] = tv;
  if (FINAL){
    out[idx] = tv;
    out[(size_t)NTOT*DIM + idx] = tv;
  }
}

extern "C" void kernel_launch(void* const* d_in, const int* in_sizes, int n_in,
                              void* d_out, int out_size, void* d_ws, size_t ws_size,
                              hipStream_t stream){
  const int*   adj_row = (const int*)  d_in[0];
  const int*   adj_col = (const int*)  d_in[1];
  const float* adj_val = (const float*)d_in[2];
  const float* pe   = (const float*)d_in[3];
  const float* ae   = (const float*)d_in[4];
  const float* qe   = (const float*)d_in[5];
  const float* Wqkv = (const float*)d_in[6];
  const float* Wo   = (const float*)d_in[7];
  const float* W1   = (const float*)d_in[8];
  const float* b1   = (const float*)d_in[9];
  const float* W2   = (const float*)d_in[10];
  const float* b2   = (const float*)d_in[11];
  const float* g1   = (const float*)d_in[12];
  const float* be1  = (const float*)d_in[13];
  const float* g2   = (const float*)d_in[14];
  const float* be2  = (const float*)d_in[15];
  float* out = (float*)d_out;

  // ---- workspace (~36.7 MB, layout unchanged) ----
  char* w = (char*)d_ws;
  float* cur  = (float*)w; w += (size_t)NTOT*DIM*4;
  float* tot  = (float*)w; w += (size_t)NTOT*DIM*4;
  float* tf   = (float*)w; w += (size_t)NTOT*DIM*4;
  float* pbuf = (float*)w; w += (size_t)NTOT*DIM*4;        // proj/ffn2 out; attn partials (2x bf16)
  float* x1   = (float*)w; w += (size_t)NTOT*DIM*4;
  u16* tbf    = (u16*)w;   w += (size_t)NTOT*DIM*2;        // spmm bf16; attn m/l
  u16* curb   = (u16*)w;   w += (size_t)NTOT*DIM*2;        // bf16 shadow of cur
  u16* x1b    = (u16*)w;   w += (size_t)NTOT*DIM*2;
  u16* hq     = (u16*)w;   w += (size_t)NTOT*FFD*2;        // qbf ∪ h
  u16* wqkvt  = (u16*)w;   w += (size_t)768*256*2;
  u16* wot    = (u16*)w;   w += (size_t)256*256*2;
  u16* w1t    = (u16*)w;   w += (size_t)1024*256*2;
  u16* w2t    = (u16*)w;   w += (size_t)256*1024*2;
  int* rowptr = (int*)w;   w += (size_t)(NTOT+1)*4;
  int* cnt    = (int*)w;   w += (size_t)NTOT*4;
  int* cursor = (int*)w;   w += (size_t)NTOT*4;
  int* ccol   = (int*)w;   w += (size_t)NEDGE*4;
  float* cval = (float*)w; w += (size_t)NEDGE*4;
  u16* qbf  = hq;
  u16* opbf = (u16*)pbuf;                      // 2 bf16 partials = 4 MB (pbuf region)
  float* mbuf = (float*)tbf;                   // [KSPLIT][NH][NTOT] f32
  float* lbuf = mbuf + (size_t)KSPLIT*NH*NTOT;

  k_zero<<<16, 256, 0, stream>>>(cnt, NTOT);
  k_embed<<<NTOT, 256, 0, stream>>>(pe, ae, qe, cur, tot, curb);
  k_hist<<<NEDGE/256, 256, 0, stream>>>(adj_row, cnt);
  k_scan<<<1, 64, 0, stream>>>(cnt, rowptr, cursor);
  k_scatter<<<NEDGE/256, 256, 0, stream>>>(adj_row, adj_col, adj_val, cursor, ccol, cval);
  k_wconv_all<<<2304, 256, 0, stream>>>(Wqkv, Wo, W1, W2, wqkvt, wot, w1t, w2t);

  for (int blk = 0; blk < 3; ++blk){
    k_spmm<<<NTOT, 256, 0, stream>>>(rowptr, ccol, cval, curb, tf, tbf);
    k_gemm64<0,0,1,0><<<dim3(768/64, NTOT/64), 256, 0, stream>>>(tbf, wqkvt, nullptr, qbf, nullptr, nullptr, NTOT, 256, 768);
    k_attn_mfma<<<dim3(NTOT/64, NH, KSPLIT), 256, 0, stream>>>(qbf, opbf, mbuf, lbuf);
    k_gemm64<0,0,0,1><<<dim3(256/64, NTOT/64), 256, 0, stream>>>(opbf, wot, nullptr, pbuf, mbuf, lbuf, NTOT, 256, 256);
    k_add_ln<1><<<NTOT, 256, 0, stream>>>(tf, pbuf, g1, be1, x1, x1b);
    k_gemm64<1,1,1,0><<<dim3(1024/64, NTOT/64), 256, 0, stream>>>(x1b, w1t, b1, hq, nullptr, nullptr, NTOT, 256, 1024);
    k_gemm64<0,1,0,0><<<dim3(256/64, NTOT/64), 256, 0, stream>>>(hq, w2t, b2, pbuf, nullptr, nullptr, NTOT, 1024, 256);
    if (blk < 2)
      k_add_ln_upd<0><<<NTOT, 256, 0, stream>>>(x1, pbuf, g2, be2, cur, tot, curb, nullptr);
    else
      k_add_ln_upd<1><<<NTOT, 256, 0, stream>>>(x1, pbuf, g2, be2, cur, tot, nullptr, out);
  }
}

// Round 22
// 468.314 us; speedup vs baseline: 1.3405x; 1.0044x over previous
//
#include <hip/hip_runtime.h>
#include <hip/hip_bf16.h>

// ProteinGNNTransformer — round 22: clean revert to r20 (best verified: 470us).
// r21's ds_read_b64_tr_b16 lane-mapping assumption was wrong (absmax 12.2);
// HW-transpose path abandoned rather than debugging blind via bench rounds.

#define NPROT 3000
#define NAA   25
#define NPROP 1071
#define NTOT  4096
#define DIM   256
#define NH    8
#define DHD   32
#define FFD   1024
#define NEDGE 131072
#define LNEPS 1e-5f
#define KSPLIT 2
#define KVQ (NTOT/KSPLIT)

typedef unsigned short u16;
typedef unsigned int u32;
typedef __attribute__((ext_vector_type(8))) short short8v;
typedef __attribute__((ext_vector_type(4))) float float4v;
typedef __attribute__((ext_vector_type(2))) unsigned int uint2v;

__device__ __forceinline__ u16 f2bu(float x){
  union { __hip_bfloat16 h; u16 u; } c; c.h = __float2bfloat16(x); return c.u;
}
__device__ __forceinline__ float bu2f(u16 u){
  union { u32 i; float f; } c; c.i = ((u32)u) << 16; return c.f;
}
__device__ __forceinline__ float4v mfma16(short8v a, short8v b, float4v c){
  return __builtin_amdgcn_mfma_f32_16x16x32_bf16(a, b, c, 0, 0, 0);
}
// pack two f32 to two bf16 (truncation) — v_perm idiom
__device__ __forceinline__ u32 packbf(float lo, float hi){
  u32 ul = __builtin_bit_cast(u32, lo);
  u32 uh = __builtin_bit_cast(u32, hi);
  return (ul >> 16) | (uh & 0xFFFF0000u);
}
// async global->LDS, 16 bytes/lane (dest = wave-uniform base + lane*16)
__device__ __forceinline__ void gload_lds16(const u16* g, u16* l){
  __builtin_amdgcn_global_load_lds(
      (const __attribute__((address_space(1))) void*)g,
      (__attribute__((address_space(3))) void*)l, 16, 0, 0);
}

// ---------------- embedding concat (+bf16 shadow of cur) ----------------
__global__ __launch_bounds__(256) void k_embed(const float* __restrict__ pe, const float* __restrict__ ae,
                                               const float* __restrict__ qe,
                                               float* __restrict__ cur, float* __restrict__ tot,
                                               u16* __restrict__ curb){
  int i = blockIdx.x*256 + threadIdx.x;
  int row = i >> 8;
  float v;
  if (row < NPROT)           v = pe[i];
  else if (row < NPROT+NAA)  v = ae[i - NPROT*DIM];
  else                       v = qe[i - (NPROT+NAA)*DIM];
  cur[i] = v; tot[i] = v; curb[i] = f2bu(v);
}

__global__ __launch_bounds__(256) void k_zero(int* __restrict__ p, int n){
  int i = blockIdx.x*256 + threadIdx.x; if (i < n) p[i] = 0;
}

// ---------------- fused weight transpose+convert ----------------
__global__ __launch_bounds__(256) void k_wconv_all(const float* __restrict__ Wqkv, const float* __restrict__ Wo,
                                                   const float* __restrict__ W1, const float* __restrict__ W2,
                                                   u16* __restrict__ wqkvt, u16* __restrict__ wot,
                                                   u16* __restrict__ w1t, u16* __restrict__ w2t){
  int b = blockIdx.x;
  const float* W; u16* Wt; int K, N, n;
  if (b < 768)       { W = Wqkv; Wt = wqkvt; K = 256;  N = 768;  n = b; }
  else if (b < 1024) { W = Wo;   Wt = wot;   K = 256;  N = 256;  n = b - 768; }
  else if (b < 2048) { W = W1;   Wt = w1t;   K = 256;  N = 1024; n = b - 1024; }
  else               { W = W2;   Wt = w2t;   K = 1024; N = 256;  n = b - 2048; }
  for (int k = threadIdx.x; k < K; k += 256)
    Wt[(size_t)n*K + k] = f2bu(W[(size_t)k*N + n]);
}

// ---------------- CSR build ----------------
__global__ __launch_bounds__(256) void k_hist(const int* __restrict__ rows, int* __restrict__ cnt){
  int e = blockIdx.x*256 + threadIdx.x; if (e < NEDGE) atomicAdd(&cnt[rows[e]], 1);
}

__global__ __launch_bounds__(64) void k_scan(const int* __restrict__ cnt, int* __restrict__ rowptr,
                                             int* __restrict__ cursor){
  int lane = threadIdx.x;
  int sum = 0;
  for (int i = 0; i < 64; ++i) sum += cnt[lane*64 + i];
  int pref = sum;
  #pragma unroll
  for (int off = 1; off < 64; off <<= 1){
    int u = __shfl_up(pref, off);
    if (lane >= off) pref += u;
  }
  int run = pref - sum;
  for (int i = 0; i < 64; ++i){
    int c = cnt[lane*64 + i];
    rowptr[lane*64 + i] = run;
    cursor[lane*64 + i] = run;
    run += c;
  }
  if (lane == 63) rowptr[NTOT] = run;
}

__global__ __launch_bounds__(256) void k_scatter(const int* __restrict__ rows, const int* __restrict__ cols,
                                                 const float* __restrict__ vals, int* __restrict__ cursor,
                                                 int* __restrict__ ccol, float* __restrict__ cval){
  int e = blockIdx.x*256 + threadIdx.x; if (e >= NEDGE) return;
  int p = atomicAdd(&cursor[rows[e]], 1);
  ccol[p] = cols[e]; cval[p] = vals[e];
}

// ---------------- SpMM (bf16 gather): f32 out + bf16 shadow ----------------
__global__ __launch_bounds__(256) void k_spmm(const int* __restrict__ rowptr, const int* __restrict__ ccol,
                                              const float* __restrict__ cval, const u16* __restrict__ xb,
                                              float* __restrict__ out, u16* __restrict__ outb){
  int r = blockIdx.x, c = threadIdx.x;
  int s = rowptr[r], e = rowptr[r+1];
  float acc = 0.f;
  for (int i = s; i < e; ++i)
    acc += cval[i] * bu2f(xb[((size_t)ccol[i] << 8) + c]);
  out[((size_t)r << 8) + c] = acc;
  outb[((size_t)r << 8) + c] = f2bu(acc);
}

// ---------------- MFMA GEMM, 64x64 tile; async staging; MERGE fuses attn merge ----------------
template<int RELU, int BIAS, int BF16OUT, int MERGE>
__global__ __launch_bounds__(256) void k_gemm64(const u16* __restrict__ A, const u16* __restrict__ Wt,
                                                const float* __restrict__ bias, void* __restrict__ Cv,
                                                const float* __restrict__ mbuf, const float* __restrict__ lbuf,
                                                int M, int K, int Nc){
  __shared__ u16 Al[64*64];
  __shared__ u16 Bl[64*64];
  const int tid = threadIdx.x;
  const int w  = tid >> 6, l = tid & 63, lr = l & 15, g = l >> 4;
  const int row0 = blockIdx.y*64, col0 = blockIdx.x*64;
  const int wm = (w >> 1)*32, wn = (w & 1)*32;
  const int sm = tid >> 2;
  const int so = (tid & 3)*2;
  const int srow = (l >> 3);
  const int soct = (l & 7) ^ srow;
  float4v acc[2][2] = {};

  for (int k0 = 0; k0 < K; k0 += 64){
    if (MERGE){
      const u16* Bs = Wt + (size_t)(col0 + sm)*K + k0 + so*8;
      int row = row0 + sm;
      #pragma unroll
      for (int j = 0; j < 2; ++j){
        int o = so + j;
        int kabs = k0 + o*8;
        int h = kabs >> 5;
        float mm0 = mbuf[(size_t)h*NTOT + row];
        float mm1 = mbuf[(size_t)(NH + h)*NTOT + row];
        float Mx = fmaxf(mm0, mm1);
        float e0 = __expf(mm0 - Mx), e1 = __expf(mm1 - Mx);
        float L = e0*lbuf[(size_t)h*NTOT + row] + e1*lbuf[(size_t)(NH + h)*NTOT + row];
        float sc0 = e0 / L, sc1 = e1 / L;
        short8v p0 = *(const short8v*)(A + (size_t)row*DIM + kabs);
        short8v p1 = *(const short8v*)(A + (size_t)NTOT*DIM + (size_t)row*DIM + kabs);
        short8v mv;
        #pragma unroll
        for (int jj = 0; jj < 8; ++jj)
          mv[jj] = (short)f2bu(sc0*bu2f((u16)p0[jj]) + sc1*bu2f((u16)p1[jj]));
        int slot = o ^ (sm & 7);
        *(short8v*)(Al + sm*64 + slot*8) = mv;
        *(short8v*)(Bl + sm*64 + slot*8) = *(const short8v*)(Bs + j*8);
      }
    } else {
      #pragma unroll
      for (int i = 0; i < 2; ++i){
        int row = 16*w + 8*i + srow;
        gload_lds16(A  + (size_t)(row0 + row)*K + k0 + soct*8, Al + (16*w + 8*i)*64);
        gload_lds16(Wt + (size_t)(col0 + row)*K + k0 + soct*8, Bl + (16*w + 8*i)*64);
      }
    }
    __syncthreads();
    #pragma unroll
    for (int kk = 0; kk < 2; ++kk){
      short8v af[2], bfr[2];
      #pragma unroll
      for (int i = 0; i < 2; ++i){
        int am = wm + 16*i + lr;
        af[i]  = *(const short8v*)(Al + am*64 + (((4*kk + g) ^ (am & 7))*8));
        int bn = wn + 16*i + lr;
        bfr[i] = *(const short8v*)(Bl + bn*64 + (((4*kk + g) ^ (bn & 7))*8));
      }
      acc[0][0] = mfma16(af[0], bfr[0], acc[0][0]);
      acc[0][1] = mfma16(af[0], bfr[1], acc[0][1]);
      acc[1][0] = mfma16(af[1], bfr[0], acc[1][0]);
      acc[1][1] = mfma16(af[1], bfr[1], acc[1][1]);
    }
    __syncthreads();
  }

  #pragma unroll
  for (int mi = 0; mi < 2; ++mi){
    #pragma unroll
    for (int ni = 0; ni < 2; ++ni){
      int col = col0 + wn + 16*ni + lr;
      float bv = BIAS ? bias[col] : 0.f;
      #pragma unroll
      for (int j = 0; j < 4; ++j){
        int row = row0 + wm + 16*mi + 4*g + j;
        float v = acc[mi][ni][j] + bv;
        if (RELU) v = fmaxf(v, 0.f);
        if (BF16OUT) ((u16*)Cv)[(size_t)row*Nc + col] = f2bu(v);
        else         ((float*)Cv)[(size_t)row*Nc + col] = v;
      }
    }
  }
}

// ---------------- MFMA flash attention, split-K x2 (r15/r20 structure) ----------------
__global__ __launch_bounds__(256) void k_attn_mfma(const u16* __restrict__ qbf,
                                                   u16* __restrict__ op,
                                                   float* __restrict__ mbuf, float* __restrict__ lbuf){
  __shared__ u16 Vt[2][32*64];
  __shared__ u16 Pl[4][16*64];
  __shared__ float Fl[4][16];
  const int h   = blockIdx.y;
  const int ks  = blockIdx.z;
  const int qb  = blockIdx.x * 64;
  const int tid = threadIdx.x;
  const int w   = tid >> 6;
  const int l   = tid & 63;
  const int lr  = l & 15;
  const int g   = l >> 4;
  const int sr  = tid >> 2;
  const int sq  = tid & 3;
  const float SC  = 0.17677669529663687f;          // 1/sqrt(32)
  const float SCL = 0.25503837f;                    // SC * log2(e)
  const float DEFER = 31.368f;                      // 8/SCL: P bounded by 2^8
  u16* opart = op + (size_t)ks*NTOT*DIM;

  short8v qf = *(const short8v*)(qbf + (size_t)(qb + 16*w + lr)*768 + h*DHD + 8*g);
  short8v ones;
  #pragma unroll
  for (int j = 0; j < 8; ++j) ones[j] = (short)0x3F80;   // bf16 1.0

  float4v oa0 = {0.f,0.f,0.f,0.f}, oa1 = {0.f,0.f,0.f,0.f};
  float4v accl = {0.f,0.f,0.f,0.f};
  float mrun = -1e30f;
  u16* pw = &Pl[w][0];

  const u16* vp = qbf + (size_t)(ks*KVQ + sr)*768 + 512 + h*DHD + 8*sq;
  const u16* kp = qbf + (size_t)(ks*KVQ + lr)*768 + 256 + h*DHD + 8*g;
  short8v vreg = *(const short8v*)vp;
  short8v kf0 = *(const short8v*)(kp);
  short8v kf1 = *(const short8v*)(kp + (size_t)16*768);
  short8v kf2 = *(const short8v*)(kp + (size_t)32*768);
  short8v kf3 = *(const short8v*)(kp + (size_t)48*768);

  const int NIT = KVQ/64;
  for (int t = 0; t < NIT; ++t){
    u16* vt = &Vt[t & 1][0];
    #pragma unroll
    for (int j = 0; j < 8; ++j){
      int row  = 8*sq + j;
      int slot = (sr >> 3) ^ j;
      vt[row*64 + slot*8 + (sr & 7)] = (u16)vreg[j];
    }
    __syncthreads();
    vp += (size_t)64*768;
    vreg = *(const short8v*)vp;

    float4v s0 = mfma16(kf0, qf, (float4v){0.f,0.f,0.f,0.f});
    float4v s1 = mfma16(kf1, qf, (float4v){0.f,0.f,0.f,0.f});
    float4v s2 = mfma16(kf2, qf, (float4v){0.f,0.f,0.f,0.f});
    float4v s3 = mfma16(kf3, qf, (float4v){0.f,0.f,0.f,0.f});
    kp += (size_t)64*768;
    kf0 = *(const short8v*)(kp);
    kf1 = *(const short8v*)(kp + (size_t)16*768);
    kf2 = *(const short8v*)(kp + (size_t)32*768);
    kf3 = *(const short8v*)(kp + (size_t)48*768);

    float m0 = fmaxf(fmaxf(fmaxf(s0[0],s0[1]),s0[2]),s0[3]);
    float m1 = fmaxf(fmaxf(fmaxf(s1[0],s1[1]),s1[2]),s1[3]);
    float m2 = fmaxf(fmaxf(fmaxf(s2[0],s2[1]),s2[2]),s2[3]);
    float m3 = fmaxf(fmaxf(fmaxf(s3[0],s3[1]),s3[2]),s3[3]);
    float tm = fmaxf(fmaxf(fmaxf(m0,m1),m2),m3);
    tm = fmaxf(tm, __shfl_xor(tm, 16));
    tm = fmaxf(tm, __shfl_xor(tm, 32));
    const bool nomax = __all(tm <= mrun + DEFER);
    float fac = 1.f;
    if (!nomax){
      float mn = fmaxf(mrun, tm);
      fac = exp2f((mrun - mn)*SCL);
      mrun = mn;
    }
    float mns = mrun*SCL;
    #pragma unroll
    for (int j = 0; j < 4; ++j){
      s0[j] = exp2f(__builtin_fmaf(s0[j], SCL, -mns));
      s1[j] = exp2f(__builtin_fmaf(s1[j], SCL, -mns));
      s2[j] = exp2f(__builtin_fmaf(s2[j], SCL, -mns));
      s3[j] = exp2f(__builtin_fmaf(s3[j], SCL, -mns));
    }

    {
      int gh = g >> 1, gl = 4*(g & 1);
      uint2v* d0 = (uint2v*)(pw + lr*64 + ((0 + gh) ^ (lr & 7))*8 + gl);
      uint2v* d1 = (uint2v*)(pw + lr*64 + ((2 + gh) ^ (lr & 7))*8 + gl);
      uint2v* d2 = (uint2v*)(pw + lr*64 + ((4 + gh) ^ (lr & 7))*8 + gl);
      uint2v* d3 = (uint2v*)(pw + lr*64 + ((6 + gh) ^ (lr & 7))*8 + gl);
      *d0 = (uint2v){packbf(s0[0],s0[1]), packbf(s0[2],s0[3])};
      *d1 = (uint2v){packbf(s1[0],s1[1]), packbf(s1[2],s1[3])};
      *d2 = (uint2v){packbf(s2[0],s2[1]), packbf(s2[2],s2[3])};
      *d3 = (uint2v){packbf(s3[0],s3[1]), packbf(s3[2],s3[3])};
    }

    if (!nomax){
      if (g == 0) Fl[w][lr] = fac;
      float fq0 = Fl[w][4*g+0], fq1 = Fl[w][4*g+1], fq2 = Fl[w][4*g+2], fq3 = Fl[w][4*g+3];
      oa0[0]*=fq0; oa0[1]*=fq1; oa0[2]*=fq2; oa0[3]*=fq3;
      oa1[0]*=fq0; oa1[1]*=fq1; oa1[2]*=fq2; oa1[3]*=fq3;
      accl[0]*=fq0; accl[1]*=fq1; accl[2]*=fq2; accl[3]*=fq3;
    }

    #pragma unroll
    for (int kk = 0; kk < 2; ++kk){
      int slotp = (4*kk + g) ^ (lr & 7);
      short8v pa = *(const short8v*)(pw + lr*64 + slotp*8);
      short8v v0 = *(const short8v*)(vt + lr*64        + slotp*8);
      short8v v1 = *(const short8v*)(vt + (lr+16)*64   + slotp*8);
      oa0  = mfma16(pa, v0, oa0);
      oa1  = mfma16(pa, v1, oa1);
      accl = mfma16(pa, ones, accl);
    }
  }

  #pragma unroll
  for (int j = 0; j < 4; ++j){
    size_t row = (size_t)(qb + 16*w + 4*g + j);
    opart[row*DIM + h*DHD + lr]      = f2bu(oa0[j]);
    opart[row*DIM + h*DHD + 16 + lr] = f2bu(oa1[j]);
  }
  if (l < 16){
    size_t mi = (size_t)(ks*NH + h)*NTOT + qb + 16*w + lr;
    mbuf[mi] = mrun*SC;
  }
  if (lr == 0){
    #pragma unroll
    for (int j = 0; j < 4; ++j){
      size_t mi = (size_t)(ks*NH + h)*NTOT + qb + 16*w + 4*g + j;
      lbuf[mi] = accl[j];
    }
  }
}

// ---------------- fused residual + LayerNorm (+bf16 shadow) ----------------
template<int DUAL>
__global__ __launch_bounds__(256) void k_add_ln(const float* __restrict__ a, const float* __restrict__ b,
                                                const float* __restrict__ g, const float* __restrict__ be,
                                                float* __restrict__ out, u16* __restrict__ out2){
  __shared__ float red[4];
  int r = blockIdx.x, c = threadIdx.x;
  float v = a[((size_t)r << 8) + c] + b[((size_t)r << 8) + c];
  float s = v;
  #pragma unroll
  for (int off = 32; off; off >>= 1) s += __shfl_down(s, off);
  if ((c & 63) == 0) red[c >> 6] = s;
  __syncthreads();
  float mean = (red[0]+red[1]+red[2]+red[3]) * (1.f/DIM);
  __syncthreads();
  float d = v - mean;
  float s2 = d*d;
  #pragma unroll
  for (int off = 32; off; off >>= 1) s2 += __shfl_down(s2, off);
  if ((c & 63) == 0) red[c >> 6] = s2;
  __syncthreads();
  float var = (red[0]+red[1]+red[2]+red[3]) * (1.f/DIM);
  float rv = d * rsqrtf(var + LNEPS) * g[c] + be[c];
  out[((size_t)r << 8) + c] = rv;
  if (DUAL) out2[((size_t)r << 8) + c] = f2bu(rv);
}

// ---------------- fused LN2 + update (+bf16 cur shadow, +final output) ----------------
template<int FINAL>
__global__ __launch_bounds__(256) void k_add_ln_upd(const float* __restrict__ a, const float* __restrict__ b,
                                                    const float* __restrict__ g, const float* __restrict__ be,
                                                    float* __restrict__ cur, float* __restrict__ tot,
                                                    u16* __restrict__ curb, float* __restrict__ out){
  __shared__ float red[4];
  int r = blockIdx.x, c = threadIdx.x;
  size_t idx = ((size_t)r << 8) + c;
  float v = a[idx] + b[idx];
  float s = v;
  #pragma unroll
  for (int off = 32; off; off >>= 1) s += __shfl_down(s, off);
  if ((c & 63) == 0) red[c >> 6] = s;
  __syncthreads();
  float mean = (red[0]+red[1]+red[2]+red[3]) * (1.f/DIM);
  __syncthreads();
  float d = v - mean;
  float s2 = d*d;
  #pragma unroll
  for (int off = 32; off; off >>= 1) s2 += __shfl_down(s2, off);
  if ((c & 63) == 0) red[c >> 6] = s2;
  __syncthreads();
  float var = (red[0]+red[1]+red[2]+red[3]) * (1.f/DIM);
  float rv = d * rsqrtf(var + LNEPS) * g[c] + be[c];
  float cu = cur[idx] + rv;
  cur[idx] = cu;
  if (!FINAL) curb[idx] = f2bu(cu);
  float tv = tot[idx] + cu;
  tot[idx] = tv;
  if (FINAL){
    out[idx] = tv;
    out[(size_t)NTOT*DIM + idx] = tv;
  }
}

extern "C" void kernel_launch(void* const* d_in, const int* in_sizes, int n_in,
                              void* d_out, int out_size, void* d_ws, size_t ws_size,
                              hipStream_t stream){
  const int*   adj_row = (const int*)  d_in[0];
  const int*   adj_col = (const int*)  d_in[1];
  const float* adj_val = (const float*)d_in[2];
  const float* pe   = (const float*)d_in[3];
  const float* ae   = (const float*)d_in[4];
  const float* qe   = (const float*)d_in[5];
  const float* Wqkv = (const float*)d_in[6];
  const float* Wo   = (const float*)d_in[7];
  const float* W1   = (const float*)d_in[8];
  const float* b1   = (const float*)d_in[9];
  const float* W2   = (const float*)d_in[10];
  const float* b2   = (const float*)d_in[11];
  const float* g1   = (const float*)d_in[12];
  const float* be1  = (const float*)d_in[13];
  const float* g2   = (const float*)d_in[14];
  const float* be2  = (const float*)d_in[15];
  float* out = (float*)d_out;

  // ---- workspace (~36.7 MB, layout unchanged) ----
  char* w = (char*)d_ws;
  float* cur  = (float*)w; w += (size_t)NTOT*DIM*4;
  float* tot  = (float*)w; w += (size_t)NTOT*DIM*4;
  float* tf   = (float*)w; w += (size_t)NTOT*DIM*4;
  float* pbuf = (float*)w; w += (size_t)NTOT*DIM*4;        // proj/ffn2 out; attn partials (2x bf16)
  float* x1   = (float*)w; w += (size_t)NTOT*DIM*4;
  u16* tbf    = (u16*)w;   w += (size_t)NTOT*DIM*2;        // spmm bf16; attn m/l
  u16* curb   = (u16*)w;   w += (size_t)NTOT*DIM*2;        // bf16 shadow of cur
  u16* x1b    = (u16*)w;   w += (size_t)NTOT*DIM*2;
  u16* hq     = (u16*)w;   w += (size_t)NTOT*FFD*2;        // qbf ∪ h
  u16* wqkvt  = (u16*)w;   w += (size_t)768*256*2;
  u16* wot    = (u16*)w;   w += (size_t)256*256*2;
  u16* w1t    = (u16*)w;   w += (size_t)1024*256*2;
  u16* w2t    = (u16*)w;   w += (size_t)256*1024*2;
  int* rowptr = (int*)w;   w += (size_t)(NTOT+1)*4;
  int* cnt    = (int*)w;   w += (size_t)NTOT*4;
  int* cursor = (int*)w;   w += (size_t)NTOT*4;
  int* ccol   = (int*)w;   w += (size_t)NEDGE*4;
  float* cval = (float*)w; w += (size_t)NEDGE*4;
  u16* qbf  = hq;
  u16* opbf = (u16*)pbuf;                      // 2 bf16 partials = 4 MB (pbuf region)
  float* mbuf = (float*)tbf;                   // [KSPLIT][NH][NTOT] f32
  float* lbuf = mbuf + (size_t)KSPLIT*NH*NTOT;

  k_zero<<<16, 256, 0, stream>>>(cnt, NTOT);
  k_embed<<<NTOT, 256, 0, stream>>>(pe, ae, qe, cur, tot, curb);
  k_hist<<<NEDGE/256, 256, 0, stream>>>(adj_row, cnt);
  k_scan<<<1, 64, 0, stream>>>(cnt, rowptr, cursor);
  k_scatter<<<NEDGE/256, 256, 0, stream>>>(adj_row, adj_col, adj_val, cursor, ccol, cval);
  k_wconv_all<<<2304, 256, 0, stream>>>(Wqkv, Wo, W1, W2, wqkvt, wot, w1t, w2t);

  for (int blk = 0; blk < 3; ++blk){
    k_spmm<<<NTOT, 256, 0, stream>>>(rowptr, ccol, cval, curb, tf, tbf);
    k_gemm64<0,0,1,0><<<dim3(768/64, NTOT/64), 256, 0, stream>>>(tbf, wqkvt, nullptr, qbf, nullptr, nullptr, NTOT, 256, 768);
    k_attn_mfma<<<dim3(NTOT/64, NH, KSPLIT), 256, 0, stream>>>(qbf, opbf, mbuf, lbuf);
    k_gemm64<0,0,0,1><<<dim3(256/64, NTOT/64), 256, 0, stream>>>(opbf, wot, nullptr, pbuf, mbuf, lbuf, NTOT, 256, 256);
    k_add_ln<1><<<NTOT, 256, 0, stream>>>(tf, pbuf, g1, be1, x1, x1b);
    k_gemm64<1,1,1,0><<<dim3(1024/64, NTOT/64), 256, 0, stream>>>(x1b, w1t, b1, hq, nullptr, nullptr, NTOT, 256, 1024);
    k_gemm64<0,1,0,0><<<dim3(256/64, NTOT/64), 256, 0, stream>>>(hq, w2t, b2, pbuf, nullptr, nullptr, NTOT, 1024, 256);
    if (blk < 2)
      k_add_ln_upd<0><<<NTOT, 256, 0, stream>>>(x1, pbuf, g2, be2, cur, tot, curb, nullptr);
    else
      k_add_ln_upd<1><<<NTOT, 256, 0, stream>>>(x1, pbuf, g2, be2, cur, tot, nullptr, out);
  }
}